// Round 3
// baseline (466.357 us; speedup 1.0000x reference)
//
#include <hip/hip_runtime.h>

typedef __bf16 bf16;
typedef __attribute__((ext_vector_type(8))) __bf16 bf16x8;
typedef __attribute__((ext_vector_type(4))) __bf16 bf16x4;
typedef __attribute__((ext_vector_type(4))) float f32x4;

#define B_    64
#define N_    197
#define C_    768
#define H_    12
#define HD_   64
#define SCALE_ 0.125f
#define NM_   (N_*N_)         // 38809
#define M_    (B_*N_)         // 12608
#define NEGI_ (-30000.0f)
#define VTP_  200             // vbufT / rpbT row pad

// ---------------- fused prep: cast x/proj_w, W_eff + bias, rpbT ----------------
// blocks [0,5016): cast; [5016,11928): weff; [11928,13748): rpbT
__global__ __launch_bounds__(256) void prep_kernel(
    const float* __restrict__ x, const float* __restrict__ pw,
    const float* __restrict__ qkv_w, const float* __restrict__ q_bias, const float* __restrict__ v_bias,
    const float* __restrict__ qa, const float* __restrict__ qb,
    const float* __restrict__ ka, const float* __restrict__ kb,
    const float* __restrict__ va, const float* __restrict__ vb,
    const float* __restrict__ table, const int* __restrict__ rpi,
    bf16* __restrict__ xbf, bf16* __restrict__ pwbf,
    bf16* __restrict__ weff, float* __restrict__ biasf, bf16* __restrict__ rpbT)
{
  const int bid = blockIdx.x, tid = threadIdx.x;
  if (bid < 5016) {
    const size_t n1 = (size_t)M_ * C_;   // 9,682,944
    size_t i8 = ((size_t)bid * 256 + tid) * 8;
    const float* src; bf16* dst; size_t off;
    if (i8 < n1) { src = x;  dst = xbf;  off = i8; }
    else         { src = pw; dst = pwbf; off = i8 - n1; }
    float4 f0 = *(const float4*)(src + off);
    float4 f1 = *(const float4*)(src + off + 4);
    bf16x8 v8;
    v8[0] = (bf16)f0.x; v8[1] = (bf16)f0.y; v8[2] = (bf16)f0.z; v8[3] = (bf16)f0.w;
    v8[4] = (bf16)f1.x; v8[5] = (bf16)f1.y; v8[6] = (bf16)f1.z; v8[7] = (bf16)f1.w;
    *(bf16x8*)(dst + off) = v8;
  } else if (bid < 11928) {
    int idx = (bid - 5016) * 256 + tid;          // < 1,769,472 exact
    int d = idx / C_, c = idx - d * C_;
    int sel = d / C_, dd = d - sel * C_;
    const float* a  = (sel == 0) ? qa : (sel == 1) ? ka : va;
    const float* bw = (sel == 0) ? qb : (sel == 1) ? kb : vb;
    float acc = qkv_w[idx];
#pragma unroll
    for (int r = 0; r < 24; ++r)
      acc += bw[dd * 24 + r] * a[r * C_ + c];
    weff[idx] = (bf16)acc;
    if (c == 0)
      biasf[d] = (sel == 0) ? q_bias[dd] : (sel == 2) ? v_bias[dd] : 0.0f;
  } else {
    int idx = (bid - 11928) * 256 + tid;
    if (idx < H_ * NM_) {
      int h = idx / NM_, nm = idx - h * NM_;
      int n = nm / N_, m = nm - n * N_;
      rpbT[((size_t)h * N_ + m) * VTP_ + n] = (bf16)table[rpi[nm] * H_ + h];
    }
  }
}

// ---------------- gemm_bt: LDS-FREE streaming MFMA GEMM ----------------
// C[M,Nn] = A[M,K] @ B[Nn,K]^T + bias. 128x128 block tile, 4 waves (2Mx2N of 64x64).
// MFMA fragments loaded DIRECTLY from global: per wave-instr, 16 rows x 64B
// fully-consumed cache lines (l15 -> row, quad -> 16B K-chunk) — attn-style streaming.
// No LDS, no barriers: 16 waves/CU stream independently; compiler free to overlap
// loads of step t+1 under MFMAs of step t (no sync points). A/B are L2/L3-resident
// (A 19.4MB in L3, B <=3.5MB in L2); XCD-chunked bijective swizzle (m204) keeps the
// A panel of co-scheduled blocks in one XCD's L2.
// R1/R2 lesson: blocks/CU 4->2->1 gave 98->132->139 us — concurrency is the lever;
// this removes the LDS cap and all barrier lockstep.
// MODE 0: scatter q(xSCALE)/k -> [B,H,N,HD]; v -> TRANSPOSED [B,H,HD,VTP_]
// MODE 1: C[m,d] = acc + biasp[d] -> f32 out
template<int MODE>
__global__ __launch_bounds__(256, 4) void gemm_bt(
    const bf16* __restrict__ A, const bf16* __restrict__ Bw,
    const float* __restrict__ biasp,
    float* __restrict__ Coutf, int M, int Nn, int K,
    bf16* __restrict__ qo, bf16* __restrict__ ko, bf16* __restrict__ vo)
{
  const int tid = threadIdx.x;
  const int lane = tid & 63, w = tid >> 6;
  const int l15 = lane & 15, quad = lane >> 4;
  const int wm = (w & 1) * 64, wn = (w >> 1) * 64;

  // XCD-chunked bijective swizzle (m204) on the linearized 2D grid:
  // consecutive wg on the SAME XCD share rowA0 (A panel) -> L2 locality.
  const int ntx = gridDim.x;
  const int nwg = ntx * gridDim.y;
  int lid = blockIdx.y * ntx + blockIdx.x;
  int xcd = lid & 7, hi = lid >> 3;
  int qq = nwg >> 3, rr = nwg & 7;
  int wg = (xcd < rr ? xcd * (qq + 1) : rr * (qq + 1) + (xcd - rr) * qq) + hi;
  const int rowB0 = (wg % ntx) * 128;
  const int rowA0 = (wg / ntx) * 128;

  // per-thread fragment row pointers (row-clamped; dup rows discarded in epilogue),
  // pre-offset by quad*16B so inner loads are ptr + kt (+imm 64B for ks=1)
  const bf16* pa[4]; const bf16* pb[4];
#pragma unroll
  for (int i = 0; i < 4; ++i) {
    int ra = rowA0 + wm + i * 16 + l15; if (ra > M - 1) ra = M - 1;
    pa[i] = A + (size_t)ra * K + quad * 8;
    int rb = rowB0 + wn + i * 16 + l15; if (rb > Nn - 1) rb = Nn - 1;
    pb[i] = Bw + (size_t)rb * K + quad * 8;
  }

  f32x4 acc[4][4] = {};

  for (int kt = 0; kt < K; kt += 64) {
#pragma unroll
    for (int ks = 0; ks < 2; ++ks) {
      bf16x8 af[4], bfr[4];
#pragma unroll
      for (int i = 0; i < 4; ++i) {
        af[i]  = *(const bf16x8*)(pa[i] + kt + ks * 32);
        bfr[i] = *(const bf16x8*)(pb[i] + kt + ks * 32);
      }
#pragma unroll
      for (int i = 0; i < 4; ++i)
#pragma unroll
        for (int j = 0; j < 4; ++j)
          acc[i][j] = __builtin_amdgcn_mfma_f32_16x16x32_bf16(af[i], bfr[j], acc[i][j], 0, 0, 0);
    }
  }

#pragma unroll
  for (int i = 0; i < 4; ++i) {
#pragma unroll
    for (int j = 0; j < 4; ++j) {
#pragma unroll
      for (int r = 0; r < 4; ++r) {
        int m = rowA0 + wm + i * 16 + quad * 4 + r;
        int d = rowB0 + wn + j * 16 + l15;
        if (m >= M) continue;
        float v = acc[i][j][r] + biasp[d];
        if (MODE == 0) {
          int b = m / N_, n = m - b * N_;
          int sel = d / C_, dd = d - sel * C_;
          int h = dd >> 6, hd = dd & 63;
          if (sel == 0)
            qo[(((size_t)b * H_ + h) * N_ + n) * HD_ + hd] = (bf16)(v * SCALE_);
          else if (sel == 1)
            ko[(((size_t)b * H_ + h) * N_ + n) * HD_ + hd] = (bf16)v;
          else
            vo[(((size_t)b * H_ + h) * HD_ + hd) * VTP_ + n] = (bf16)v;   // transposed
        } else {
          Coutf[(size_t)m * Nn + d] = v;
        }
      }
    }
  }
}

// ---------------- attention: per (qtile, h, b) block, barrier-free, max-free softmax ----------------
#define SW 232   // P row stride (bf16 elems); PV consumes cols 0..223
__global__ __launch_bounds__(256) void attn_kernel(
    const bf16* __restrict__ q, const bf16* __restrict__ k, const bf16* __restrict__ vT_g,
    const bf16* __restrict__ rpbT, bf16* __restrict__ out)
{
  __shared__ __align__(16) bf16 s_lds[64 * SW];   // P tile (each wave owns its 16 rows)

  const int tid = threadIdx.x;
  const int lane = tid & 63, w = tid >> 6;
  const int l15 = lane & 15, quad = lane >> 4;
  const int qt = blockIdx.x, h = blockIdx.y, b = blockIdx.z;
  const size_t bh = ((size_t)b * H_ + h) * N_ * HD_;
  const bf16* qb = q + bh;
  const bf16* kb = k + bh;
  const bf16* vg = vT_g + ((size_t)b * H_ + h) * HD_ * VTP_;

  // zero this wave's P pad cols [208,224)  (QK pass writes cols 0..207)
  if (quad < 2)
    *(uint4*)(&s_lds[(w * 16 + l15) * SW + 208 + quad * 8]) = (uint4){0, 0, 0, 0};

  // ---- fused pass: S = Q K^T + rpb, P = exp(S), rowsum ----
  const int row0 = qt * 64 + w * 16;
  int qm = row0 + l15; if (qm > N_ - 1) qm = N_ - 1;
  bf16x8 aq0 = *(const bf16x8*)(qb + qm * HD_ + quad * 8);
  bf16x8 aq1 = *(const bf16x8*)(qb + qm * HD_ + 32 + quad * 8);

  int rbase = row0 + quad * 4; if (rbase > N_ - 1) rbase = N_ - 1;

  float sum[4] = {0.f, 0.f, 0.f, 0.f};
#pragma unroll
  for (int jt = 0; jt < 13; ++jt) {
    int col = jt * 16 + l15;
    int kn = col; if (kn > N_ - 1) kn = N_ - 1;
    bf16x8 bk0 = *(const bf16x8*)(kb + kn * HD_ + quad * 8);
    bf16x8 bk1 = *(const bf16x8*)(kb + kn * HD_ + 32 + quad * 8);
    bf16x4 rb = *(const bf16x4*)(rpbT + ((size_t)h * N_ + kn) * VTP_ + rbase);
    f32x4 s = {0.f, 0.f, 0.f, 0.f};
    s = __builtin_amdgcn_mfma_f32_16x16x32_bf16(aq0, bk0, s, 0, 0, 0);
    s = __builtin_amdgcn_mfma_f32_16x16x32_bf16(aq1, bk1, s, 0, 0, 0);
#pragma unroll
    for (int r = 0; r < 4; ++r) {
      int row = row0 + quad * 4 + r;
      // scores are O(10); pads get -30000 -> exp underflows to exactly 0
      float sv = (col < N_ && row < N_) ? (s[r] + (float)rb[r]) : NEGI_;
      float p = __expf(sv);
      bf16 pb = (bf16)p;
      s_lds[(w * 16 + quad * 4 + r) * SW + col] = pb;
      sum[r] += (float)pb;
    }
  }

  // prefetch phase-B kk=0 V fragments into the shuffle-latency shadow
  bf16x8 bv0[4];
#pragma unroll
  for (int j2 = 0; j2 < 4; ++j2)
    bv0[j2] = *(const bf16x8*)(vg + (j2 * 16 + l15) * VTP_ + quad * 8);

#pragma unroll
  for (int r = 0; r < 4; ++r) {
    sum[r] += __shfl_xor(sum[r], 1);
    sum[r] += __shfl_xor(sum[r], 2);
    sum[r] += __shfl_xor(sum[r], 4);
    sum[r] += __shfl_xor(sum[r], 8);
  }
  float inv[4];
#pragma unroll
  for (int r = 0; r < 4; ++r) inv[r] = 1.0f / fmaxf(sum[r], 1e-20f);

  // ---- phase B: O = P @ V  (V^T fragments straight from global; pads hit exact-zero P) ----
  f32x4 o[4] = {};
  {
    bf16x8 ap = *(const bf16x8*)(&s_lds[(w * 16 + l15) * SW + quad * 8]);
#pragma unroll
    for (int j2 = 0; j2 < 4; ++j2)
      o[j2] = __builtin_amdgcn_mfma_f32_16x16x32_bf16(ap, bv0[j2], o[j2], 0, 0, 0);
  }
#pragma unroll
  for (int kk = 1; kk < 7; ++kk) {
    bf16x8 ap = *(const bf16x8*)(&s_lds[(w * 16 + l15) * SW + kk * 32 + quad * 8]);
#pragma unroll
    for (int j2 = 0; j2 < 4; ++j2) {
      bf16x8 bv = *(const bf16x8*)(vg + (j2 * 16 + l15) * VTP_ + kk * 32 + quad * 8);
      o[j2] = __builtin_amdgcn_mfma_f32_16x16x32_bf16(ap, bv, o[j2], 0, 0, 0);
    }
  }
#pragma unroll
  for (int j2 = 0; j2 < 4; ++j2) {
#pragma unroll
    for (int r = 0; r < 4; ++r) {
      int row = qt * 64 + w * 16 + quad * 4 + r;
      int hd = j2 * 16 + l15;
      if (row < N_)
        out[((size_t)b * N_ + row) * C_ + h * HD_ + hd] = (bf16)(o[j2][r] * inv[r]);
    }
  }
}

// ---------------- launch ----------------
extern "C" void kernel_launch(void* const* d_in, const int* in_sizes, int n_in,
                              void* d_out, int out_size, void* d_ws, size_t ws_size,
                              hipStream_t stream)
{
  const float* x      = (const float*)d_in[0];
  const float* qkv_w  = (const float*)d_in[1];
  const float* q_bias = (const float*)d_in[2];
  const float* v_bias = (const float*)d_in[3];
  const float* q_la   = (const float*)d_in[4];
  const float* q_lb   = (const float*)d_in[5];
  const float* k_la   = (const float*)d_in[6];
  const float* k_lb   = (const float*)d_in[7];
  const float* v_la   = (const float*)d_in[8];
  const float* v_lb   = (const float*)d_in[9];
  const float* rpt    = (const float*)d_in[10];
  const float* proj_w = (const float*)d_in[11];
  const float* proj_b = (const float*)d_in[12];
  const int*   rpi    = (const int*)d_in[13];
  float* out = (float*)d_out;

  char* ws = (char*)d_ws;
  // layout (16B-aligned); xbf dead after gemm<0>, reused as aout
  bf16*  xbf   = (bf16*)(ws);                         // 19,365,888 B
  bf16*  aout  = (bf16*)(ws);                         // alias
  bf16*  weff  = (bf16*)(ws + 19365888);              //  3,538,944 B
  float* biasf = (float*)(ws + 22904832);             //      9,216 B
  bf16*  pwbf  = (bf16*)(ws + 22914048);              //  1,179,648 B
  bf16*  qbuf  = (bf16*)(ws + 24093696);              // 19,365,888 B
  bf16*  kbuf  = (bf16*)(ws + 43459584);              // 19,365,888 B
  bf16*  vbufT = (bf16*)(ws + 62825472);              // 19,660,800 (+128 slack)
  bf16*  rpbT  = (bf16*)(ws + 82486400);              // 945,600
  // total ws use ≈ 83.4 MB

  prep_kernel<<<13748, 256, 0, stream>>>(
      x, proj_w, qkv_w, q_bias, v_bias, q_la, q_lb, k_la, k_lb, v_la, v_lb,
      rpt, rpi, xbf, pwbf, weff, biasf, rpbT);

  gemm_bt<0><<<dim3(18, 99), 256, 0, stream>>>(
      xbf, weff, biasf, nullptr, M_, 3 * C_, C_, qbuf, kbuf, vbufT);

  attn_kernel<<<dim3(4, H_, B_), 256, 0, stream>>>(qbuf, kbuf, vbufT, rpbT, aout);

  gemm_bt<1><<<dim3(6, 99), 256, 0, stream>>>(
      aout, pwbf, proj_b, out, M_, C_, C_, nullptr, nullptr, nullptr);
}

// Round 4
// 318.215 us; speedup vs baseline: 1.4655x; 1.4655x over previous
//
#include <hip/hip_runtime.h>

typedef __bf16 bf16;
typedef __attribute__((ext_vector_type(8))) __bf16 bf16x8;
typedef __attribute__((ext_vector_type(4))) __bf16 bf16x4;
typedef __attribute__((ext_vector_type(4))) float f32x4;

#define B_    64
#define N_    197
#define C_    768
#define H_    12
#define HD_   64
#define SCALE_ 0.125f
#define NM_   (N_*N_)         // 38809
#define M_    (B_*N_)         // 12608
#define NEGI_ (-30000.0f)
#define VTP_  200             // vbufT / rpbT row pad

#define GLL16(gptr, lptr) \
  __builtin_amdgcn_global_load_lds((const __attribute__((address_space(1))) unsigned int*)(gptr), \
                                   (__attribute__((address_space(3))) unsigned int*)(lptr), 16, 0, 0)

// ---------------- fused prep: cast x/proj_w, W_eff + bias, rpbT ----------------
// blocks [0,5016): cast; [5016,11928): weff; [11928,13748): rpbT
__global__ __launch_bounds__(256) void prep_kernel(
    const float* __restrict__ x, const float* __restrict__ pw,
    const float* __restrict__ qkv_w, const float* __restrict__ q_bias, const float* __restrict__ v_bias,
    const float* __restrict__ qa, const float* __restrict__ qb,
    const float* __restrict__ ka, const float* __restrict__ kb,
    const float* __restrict__ va, const float* __restrict__ vb,
    const float* __restrict__ table, const int* __restrict__ rpi,
    bf16* __restrict__ xbf, bf16* __restrict__ pwbf,
    bf16* __restrict__ weff, float* __restrict__ biasf, bf16* __restrict__ rpbT)
{
  const int bid = blockIdx.x, tid = threadIdx.x;
  if (bid < 5016) {
    const size_t n1 = (size_t)M_ * C_;   // 9,682,944
    size_t i8 = ((size_t)bid * 256 + tid) * 8;
    const float* src; bf16* dst; size_t off;
    if (i8 < n1) { src = x;  dst = xbf;  off = i8; }
    else         { src = pw; dst = pwbf; off = i8 - n1; }
    float4 f0 = *(const float4*)(src + off);
    float4 f1 = *(const float4*)(src + off + 4);
    bf16x8 v8;
    v8[0] = (bf16)f0.x; v8[1] = (bf16)f0.y; v8[2] = (bf16)f0.z; v8[3] = (bf16)f0.w;
    v8[4] = (bf16)f1.x; v8[5] = (bf16)f1.y; v8[6] = (bf16)f1.z; v8[7] = (bf16)f1.w;
    *(bf16x8*)(dst + off) = v8;
  } else if (bid < 11928) {
    int idx = (bid - 5016) * 256 + tid;          // < 1,769,472 exact
    int d = idx / C_, c = idx - d * C_;
    int sel = d / C_, dd = d - sel * C_;
    const float* a  = (sel == 0) ? qa : (sel == 1) ? ka : va;
    const float* bw = (sel == 0) ? qb : (sel == 1) ? kb : vb;
    float acc = qkv_w[idx];
#pragma unroll
    for (int r = 0; r < 24; ++r)
      acc += bw[dd * 24 + r] * a[r * C_ + c];
    weff[idx] = (bf16)acc;
    if (c == 0)
      biasf[d] = (sel == 0) ? q_bias[dd] : (sel == 2) ? v_bias[dd] : 0.0f;
  } else {
    int idx = (bid - 11928) * 256 + tid;
    if (idx < H_ * NM_) {
      int h = idx / NM_, nm = idx - h * NM_;
      int n = nm / N_, m = nm - n * N_;
      rpbT[((size_t)h * N_ + m) * VTP_ + n] = (bf16)table[rpi[nm] * H_ + h];
    }
  }
}

// ---------------- gemm_bt: C[M,Nn] = A[M,K] @ B[Nn,K]^T, bf16 operands ----------------
// grid: (Nn/128, ceil(M/128)) 2D, N-tile fastest. 128x128 tile, 4 waves.
// R0-R3 scorecard (gemm<0>): R0 2-barrier 32KB/4-5blk = 98us; 256^2-8ph 128KB/1blk = 139;
// dbuf BK64 64KB/2blk = 132; LDS-free = 225 (latency-chained). Occupancy dominates.
// This round: BK=32 DOUBLE-BUFFER in the SAME 32KB -> R0 occupancy (5 blk/CU cap)
// PLUS R2's 1-deep prefetch (the untested cell):
//   prologue: STAGE(buf0, t=0); vmcnt(0); barrier
//   iter t:   STAGE(buf^1, t+1) [4 GLL16/wave fly under compute]
//             ds_read(buf) + 16 MFMA  [hw lgkmcnt orders reads->mfma]
//             vmcnt(0); s_barrier     [drain hidden under compute, 1 barrier/step]
// Barrier count unchanged vs R0 (24/block); stage latency now overlapped.
// Race: reads of buf complete before own-wave barrier; writes to buf only after it (R2-proven).
// LDS swizzle (both-sides involution, rule #21): granule cb' = cb ^ ((r>>1)&3);
// ds_read bank-balance: 8 bank-quads x 8 lanes = fully balanced.
// MODE 0: scatter q(xSCALE)/k -> [B,H,N,HD]; v -> TRANSPOSED [B,H,HD,VTP_]
// MODE 1: C[m,d] = acc + biasp[d] -> f32 out
template<int MODE>
__global__ __launch_bounds__(256, 4) void gemm_bt(
    const bf16* __restrict__ A, const bf16* __restrict__ Bw,
    const float* __restrict__ biasp,
    float* __restrict__ Coutf, int M, int Nn, int K,
    bf16* __restrict__ qo, bf16* __restrict__ ko, bf16* __restrict__ vo)
{
  __shared__ __align__(16) bf16 As[2][128 * 32];   // 8 KiB each
  __shared__ __align__(16) bf16 Bs[2][128 * 32];   // total 32 KiB
  const int tid = threadIdx.x;
  const int lane = tid & 63, w = tid >> 6;
  const int l15 = lane & 15, quad = lane >> 4;
  const int wm = (w & 1) * 64, wn = (w >> 1) * 64;
  const int rowA0 = blockIdx.y * 128;   // M-tile
  const int rowB0 = blockIdx.x * 128;   // N-tile (fastest-varying)
  const int NT = K >> 5;                // BK=32 K-steps
  const int Mm = M - 1, Nm = Nn - 1;

  f32x4 acc[4][4] = {};

  // stage one 128x32 A-tile + B-tile of K-step t into buffer p.
  // lin enumerates (row r = lin>>2, 16B-granule cb = lin&3); 4 lanes cover one
  // row's full 64B -> coalesced 64B segments. LDS dest linear (GLL16 rule);
  // swizzle applied on the GLOBAL column granule (rule #21).
  auto stageAB = [&](int t, int p) {
    const int kt = t * 32;
#pragma unroll
    for (int i = 0; i < 2; ++i) {
      int lin = (w * 2 + i) * 64 + lane;       // 0..511
      int r  = lin >> 2;                       // 0..127
      int cb = lin & 3;                        // 16B granule in row
      int csw = ((cb ^ ((r >> 1) & 3)) << 3);  // swizzled global column (elems)
      int ga = rowA0 + r; if (ga > Mm) ga = Mm;
      GLL16(A + (size_t)ga * K + kt + csw, &As[p][lin * 8]);
      int gb = rowB0 + r; if (gb > Nm) gb = Nm;
      GLL16(Bw + (size_t)gb * K + kt + csw, &Bs[p][lin * 8]);
    }
  };

  stageAB(0, 0);
  asm volatile("s_waitcnt vmcnt(0)" ::: "memory");
  __builtin_amdgcn_s_barrier();
  __builtin_amdgcn_sched_barrier(0);

  const int sg = (l15 >> 1) & 3;               // read-side swizzle term (= (row>>1)&3)

  for (int t = 0; t < NT; ++t) {
    const int p = t & 1;
    if (t + 1 < NT) stageAB(t + 1, p ^ 1);     // prefetch flies under compute
    {
      const int gq = (quad ^ sg) << 3;         // swizzled granule offset (elems)
      bf16x8 af[4], bfr[4];
#pragma unroll
      for (int i = 0; i < 4; ++i)
        af[i]  = *(const bf16x8*)(&As[p][(wm + i * 16 + l15) * 32 + gq]);
#pragma unroll
      for (int j = 0; j < 4; ++j)
        bfr[j] = *(const bf16x8*)(&Bs[p][(wn + j * 16 + l15) * 32 + gq]);
#pragma unroll
      for (int i = 0; i < 4; ++i)
#pragma unroll
        for (int j = 0; j < 4; ++j)
          acc[i][j] = __builtin_amdgcn_mfma_f32_16x16x32_bf16(af[i], bfr[j], acc[i][j], 0, 0, 0);
    }
    if (t + 1 < NT) asm volatile("s_waitcnt vmcnt(0)" ::: "memory");
    __builtin_amdgcn_s_barrier();
    __builtin_amdgcn_sched_barrier(0);
  }

#pragma unroll
  for (int i = 0; i < 4; ++i) {
#pragma unroll
    for (int j = 0; j < 4; ++j) {
#pragma unroll
      for (int r = 0; r < 4; ++r) {
        int m = rowA0 + wm + i * 16 + quad * 4 + r;
        int d = rowB0 + wn + j * 16 + l15;
        if (m >= M) continue;
        float v = acc[i][j][r] + biasp[d];
        if (MODE == 0) {
          int b = m / N_, n = m - b * N_;
          int sel = d / C_, dd = d - sel * C_;
          int h = dd >> 6, hd = dd & 63;
          if (sel == 0)
            qo[(((size_t)b * H_ + h) * N_ + n) * HD_ + hd] = (bf16)(v * SCALE_);
          else if (sel == 1)
            ko[(((size_t)b * H_ + h) * N_ + n) * HD_ + hd] = (bf16)v;
          else
            vo[(((size_t)b * H_ + h) * HD_ + hd) * VTP_ + n] = (bf16)v;   // transposed
        } else {
          Coutf[(size_t)m * Nn + d] = v;
        }
      }
    }
  }
}

// ---------------- attention: per (qtile, h, b) block, barrier-free, max-free softmax ----------------
#define SW 232   // P row stride (bf16 elems); PV consumes cols 0..223
__global__ __launch_bounds__(256) void attn_kernel(
    const bf16* __restrict__ q, const bf16* __restrict__ k, const bf16* __restrict__ vT_g,
    const bf16* __restrict__ rpbT, bf16* __restrict__ out)
{
  __shared__ __align__(16) bf16 s_lds[64 * SW];   // P tile (each wave owns its 16 rows)

  const int tid = threadIdx.x;
  const int lane = tid & 63, w = tid >> 6;
  const int l15 = lane & 15, quad = lane >> 4;
  const int qt = blockIdx.x, h = blockIdx.y, b = blockIdx.z;
  const size_t bh = ((size_t)b * H_ + h) * N_ * HD_;
  const bf16* qb = q + bh;
  const bf16* kb = k + bh;
  const bf16* vg = vT_g + ((size_t)b * H_ + h) * HD_ * VTP_;

  // zero this wave's P pad cols [208,224)  (QK pass writes cols 0..207)
  if (quad < 2)
    *(uint4*)(&s_lds[(w * 16 + l15) * SW + 208 + quad * 8]) = (uint4){0, 0, 0, 0};

  // ---- fused pass: S = Q K^T + rpb, P = exp(S), rowsum ----
  const int row0 = qt * 64 + w * 16;
  int qm = row0 + l15; if (qm > N_ - 1) qm = N_ - 1;
  bf16x8 aq0 = *(const bf16x8*)(qb + qm * HD_ + quad * 8);
  bf16x8 aq1 = *(const bf16x8*)(qb + qm * HD_ + 32 + quad * 8);

  int rbase = row0 + quad * 4; if (rbase > N_ - 1) rbase = N_ - 1;

  float sum[4] = {0.f, 0.f, 0.f, 0.f};
#pragma unroll
  for (int jt = 0; jt < 13; ++jt) {
    int col = jt * 16 + l15;
    int kn = col; if (kn > N_ - 1) kn = N_ - 1;
    bf16x8 bk0 = *(const bf16x8*)(kb + kn * HD_ + quad * 8);
    bf16x8 bk1 = *(const bf16x8*)(kb + kn * HD_ + 32 + quad * 8);
    bf16x4 rb = *(const bf16x4*)(rpbT + ((size_t)h * N_ + kn) * VTP_ + rbase);
    f32x4 s = {0.f, 0.f, 0.f, 0.f};
    s = __builtin_amdgcn_mfma_f32_16x16x32_bf16(aq0, bk0, s, 0, 0, 0);
    s = __builtin_amdgcn_mfma_f32_16x16x32_bf16(aq1, bk1, s, 0, 0, 0);
#pragma unroll
    for (int r = 0; r < 4; ++r) {
      int row = row0 + quad * 4 + r;
      // scores are O(10); pads get -30000 -> exp underflows to exactly 0
      float sv = (col < N_ && row < N_) ? (s[r] + (float)rb[r]) : NEGI_;
      float p = __expf(sv);
      bf16 pb = (bf16)p;
      s_lds[(w * 16 + quad * 4 + r) * SW + col] = pb;
      sum[r] += (float)pb;
    }
  }

  // prefetch phase-B kk=0 V fragments into the shuffle-latency shadow
  bf16x8 bv0[4];
#pragma unroll
  for (int j2 = 0; j2 < 4; ++j2)
    bv0[j2] = *(const bf16x8*)(vg + (j2 * 16 + l15) * VTP_ + quad * 8);

#pragma unroll
  for (int r = 0; r < 4; ++r) {
    sum[r] += __shfl_xor(sum[r], 1);
    sum[r] += __shfl_xor(sum[r], 2);
    sum[r] += __shfl_xor(sum[r], 4);
    sum[r] += __shfl_xor(sum[r], 8);
  }
  float inv[4];
#pragma unroll
  for (int r = 0; r < 4; ++r) inv[r] = 1.0f / fmaxf(sum[r], 1e-20f);

  // ---- phase B: O = P @ V  (V^T fragments straight from global; pads hit exact-zero P) ----
  f32x4 o[4] = {};
  {
    bf16x8 ap = *(const bf16x8*)(&s_lds[(w * 16 + l15) * SW + quad * 8]);
#pragma unroll
    for (int j2 = 0; j2 < 4; ++j2)
      o[j2] = __builtin_amdgcn_mfma_f32_16x16x32_bf16(ap, bv0[j2], o[j2], 0, 0, 0);
  }
#pragma unroll
  for (int kk = 1; kk < 7; ++kk) {
    bf16x8 ap = *(const bf16x8*)(&s_lds[(w * 16 + l15) * SW + kk * 32 + quad * 8]);
#pragma unroll
    for (int j2 = 0; j2 < 4; ++j2) {
      bf16x8 bv = *(const bf16x8*)(vg + (j2 * 16 + l15) * VTP_ + kk * 32 + quad * 8);
      o[j2] = __builtin_amdgcn_mfma_f32_16x16x32_bf16(ap, bv, o[j2], 0, 0, 0);
    }
  }
#pragma unroll
  for (int j2 = 0; j2 < 4; ++j2) {
#pragma unroll
    for (int r = 0; r < 4; ++r) {
      int row = qt * 64 + w * 16 + quad * 4 + r;
      int hd = j2 * 16 + l15;
      if (row < N_)
        out[((size_t)b * N_ + row) * C_ + h * HD_ + hd] = (bf16)(o[j2][r] * inv[r]);
    }
  }
}

// ---------------- launch ----------------
extern "C" void kernel_launch(void* const* d_in, const int* in_sizes, int n_in,
                              void* d_out, int out_size, void* d_ws, size_t ws_size,
                              hipStream_t stream)
{
  const float* x      = (const float*)d_in[0];
  const float* qkv_w  = (const float*)d_in[1];
  const float* q_bias = (const float*)d_in[2];
  const float* v_bias = (const float*)d_in[3];
  const float* q_la   = (const float*)d_in[4];
  const float* q_lb   = (const float*)d_in[5];
  const float* k_la   = (const float*)d_in[6];
  const float* k_lb   = (const float*)d_in[7];
  const float* v_la   = (const float*)d_in[8];
  const float* v_lb   = (const float*)d_in[9];
  const float* rpt    = (const float*)d_in[10];
  const float* proj_w = (const float*)d_in[11];
  const float* proj_b = (const float*)d_in[12];
  const int*   rpi    = (const int*)d_in[13];
  float* out = (float*)d_out;

  char* ws = (char*)d_ws;
  // layout (16B-aligned); xbf dead after gemm<0>, reused as aout
  bf16*  xbf   = (bf16*)(ws);                         // 19,365,888 B
  bf16*  aout  = (bf16*)(ws);                         // alias
  bf16*  weff  = (bf16*)(ws + 19365888);              //  3,538,944 B
  float* biasf = (float*)(ws + 22904832);             //      9,216 B
  bf16*  pwbf  = (bf16*)(ws + 22914048);              //  1,179,648 B
  bf16*  qbuf  = (bf16*)(ws + 24093696);              // 19,365,888 B
  bf16*  kbuf  = (bf16*)(ws + 43459584);              // 19,365,888 B
  bf16*  vbufT = (bf16*)(ws + 62825472);              // 19,660,800 (+128 slack)
  bf16*  rpbT  = (bf16*)(ws + 82486400);              // 945,600
  // total ws use ≈ 83.4 MB

  prep_kernel<<<13748, 256, 0, stream>>>(
      x, proj_w, qkv_w, q_bias, v_bias, q_la, q_lb, k_la, k_lb, v_la, v_lb,
      rpt, rpi, xbf, pwbf, weff, biasf, rpbT);

  gemm_bt<0><<<dim3(18, 99), 256, 0, stream>>>(
      xbf, weff, biasf, nullptr, M_, 3 * C_, C_, qbuf, kbuf, vbufT);

  attn_kernel<<<dim3(4, H_, B_), 256, 0, stream>>>(qbuf, kbuf, vbufT, rpbT, aout);

  gemm_bt<1><<<dim3(6, 99), 256, 0, stream>>>(
      aout, pwbf, proj_b, out, M_, C_, C_, nullptr, nullptr, nullptr);
}

// Round 5
// 304.601 us; speedup vs baseline: 1.5310x; 1.0447x over previous
//
#include <hip/hip_runtime.h>

typedef __bf16 bf16;
typedef __attribute__((ext_vector_type(8))) __bf16 bf16x8;
typedef __attribute__((ext_vector_type(4))) __bf16 bf16x4;
typedef __attribute__((ext_vector_type(4))) float f32x4;

#define B_    64
#define N_    197
#define C_    768
#define H_    12
#define HD_   64
#define SCALE_ 0.125f
#define NM_   (N_*N_)         // 38809
#define M_    (B_*N_)         // 12608
#define NEGI_ (-30000.0f)
#define VTP_  200             // vbufT / rpbT row pad

#define GLL16(gptr, lptr) \
  __builtin_amdgcn_global_load_lds((const __attribute__((address_space(1))) unsigned int*)(gptr), \
                                   (__attribute__((address_space(3))) unsigned int*)(lptr), 16, 0, 0)

// ---------------- fused prep: cast x/proj_w, W_eff + bias, rpbT ----------------
// blocks [0,5016): cast; [5016,11928): weff; [11928,13748): rpbT
__global__ __launch_bounds__(256) void prep_kernel(
    const float* __restrict__ x, const float* __restrict__ pw,
    const float* __restrict__ qkv_w, const float* __restrict__ q_bias, const float* __restrict__ v_bias,
    const float* __restrict__ qa, const float* __restrict__ qb,
    const float* __restrict__ ka, const float* __restrict__ kb,
    const float* __restrict__ va, const float* __restrict__ vb,
    const float* __restrict__ table, const int* __restrict__ rpi,
    bf16* __restrict__ xbf, bf16* __restrict__ pwbf,
    bf16* __restrict__ weff, float* __restrict__ biasf, bf16* __restrict__ rpbT)
{
  const int bid = blockIdx.x, tid = threadIdx.x;
  if (bid < 5016) {
    const size_t n1 = (size_t)M_ * C_;   // 9,682,944
    size_t i8 = ((size_t)bid * 256 + tid) * 8;
    const float* src; bf16* dst; size_t off;
    if (i8 < n1) { src = x;  dst = xbf;  off = i8; }
    else         { src = pw; dst = pwbf; off = i8 - n1; }
    float4 f0 = *(const float4*)(src + off);
    float4 f1 = *(const float4*)(src + off + 4);
    bf16x8 v8;
    v8[0] = (bf16)f0.x; v8[1] = (bf16)f0.y; v8[2] = (bf16)f0.z; v8[3] = (bf16)f0.w;
    v8[4] = (bf16)f1.x; v8[5] = (bf16)f1.y; v8[6] = (bf16)f1.z; v8[7] = (bf16)f1.w;
    *(bf16x8*)(dst + off) = v8;
  } else if (bid < 11928) {
    int idx = (bid - 5016) * 256 + tid;          // < 1,769,472 exact
    int d = idx / C_, c = idx - d * C_;
    int sel = d / C_, dd = d - sel * C_;
    const float* a  = (sel == 0) ? qa : (sel == 1) ? ka : va;
    const float* bw = (sel == 0) ? qb : (sel == 1) ? kb : vb;
    float acc = qkv_w[idx];
#pragma unroll
    for (int r = 0; r < 24; ++r)
      acc += bw[dd * 24 + r] * a[r * C_ + c];
    weff[idx] = (bf16)acc;
    if (c == 0)
      biasf[d] = (sel == 0) ? q_bias[dd] : (sel == 2) ? v_bias[dd] : 0.0f;
  } else {
    int idx = (bid - 11928) * 256 + tid;
    if (idx < H_ * NM_) {
      int h = idx / NM_, nm = idx - h * NM_;
      int n = nm / N_, m = nm - n * N_;
      rpbT[((size_t)h * N_ + m) * VTP_ + n] = (bf16)table[rpi[nm] * H_ + h];
    }
  }
}

// ---------------- gemm_bt: C[M,Nn] = A[M,K] @ B[Nn,K]^T, bf16 operands ----------------
// grid: (Nn/128, ceil(M/128)) 2D, N-tile fastest. 128x128 tile.
// Scorecard (gemm<0>): R0 2-barrier/4w/32KB = 98us; BK32-dbuf = 110; BK64-dbuf = 132;
// 256^2-8ph = 139; LDS-free = 225. Inter-block wave overlap is the carrying mechanism;
// every intra-block pipelining variant lost. This round: the ONE untried occupancy axis —
// 8 waves/block (512 thr) at IDENTICAL tile/LDS/barrier structure. Wave split 2Mx4N
// (64x32 each, acc 4x2); 4 blocks/CU x 8 waves = 32 waves/CU = full wave-slot cap
// (R0 reached only 16-20). __launch_bounds__(512,8) caps at 64 VGPR (acc halves to 32).
// MODE 0: scatter q(xSCALE)/k -> [B,H,N,HD]; v -> TRANSPOSED [B,H,HD,VTP_]
// MODE 1: C[m,d] = acc + biasp[d] -> f32 out
template<int MODE>
__global__ __launch_bounds__(512, 8) void gemm_bt(
    const bf16* __restrict__ A, const bf16* __restrict__ Bw,
    const float* __restrict__ biasp,
    float* __restrict__ Coutf, int M, int Nn, int K,
    bf16* __restrict__ qo, bf16* __restrict__ ko, bf16* __restrict__ vo)
{
  __shared__ __align__(16) bf16 As[128 * 64];
  __shared__ __align__(16) bf16 Bs[128 * 64];
  const int tid = threadIdx.x;
  const int lane = tid & 63, w = tid >> 6;          // 8 waves
  const int l15 = lane & 15, quad = lane >> 4;
  const int wm = (w & 1) * 64;                      // M half (64 rows)
  const int wn = (w >> 1) * 32;                     // N quarter (32 cols)
  const int rowA0 = blockIdx.y * 128;   // M-tile
  const int rowB0 = blockIdx.x * 128;   // N-tile (fastest-varying)

  f32x4 acc[4][2] = {};

  for (int kt = 0; kt < K; kt += 64) {
#pragma unroll
    for (int i = 0; i < 2; ++i) {
      int lin = i * 512 + tid;                 // 0..1023
      int r  = lin >> 3;                       // 0..127
      int cb = lin & 7;                        // LDS column block
      int csw = ((cb ^ (r & 7)) << 3);         // swizzled global column (elems)
      int ga = rowA0 + r; if (ga > M - 1) ga = M - 1;
      GLL16(A + (size_t)ga * K + kt + csw, &As[lin * 8]);
      int gb = rowB0 + r; if (gb > Nn - 1) gb = Nn - 1;
      GLL16(Bw + (size_t)gb * K + kt + csw, &Bs[lin * 8]);
    }
    __syncthreads();
#pragma unroll
    for (int ks = 0; ks < 2; ++ks) {
      const int cb = ks * 4 + quad;            // k-block 0..7
      const int sw = (cb ^ (l15 & 7)) << 3;
      bf16x8 af[4], bfr[2];
#pragma unroll
      for (int i = 0; i < 4; ++i)
        af[i] = *(const bf16x8*)(&As[(wm + i * 16 + l15) * 64 + sw]);
#pragma unroll
      for (int j = 0; j < 2; ++j)
        bfr[j] = *(const bf16x8*)(&Bs[(wn + j * 16 + l15) * 64 + sw]);
#pragma unroll
      for (int i = 0; i < 4; ++i)
#pragma unroll
        for (int j = 0; j < 2; ++j)
          acc[i][j] = __builtin_amdgcn_mfma_f32_16x16x32_bf16(af[i], bfr[j], acc[i][j], 0, 0, 0);
    }
    __syncthreads();
  }

#pragma unroll
  for (int i = 0; i < 4; ++i) {
#pragma unroll
    for (int j = 0; j < 2; ++j) {
#pragma unroll
      for (int r = 0; r < 4; ++r) {
        int m = rowA0 + wm + i * 16 + quad * 4 + r;
        int d = rowB0 + wn + j * 16 + l15;
        if (m >= M) continue;
        float v = acc[i][j][r] + biasp[d];
        if (MODE == 0) {
          int b = m / N_, n = m - b * N_;
          int sel = d / C_, dd = d - sel * C_;
          int h = dd >> 6, hd = dd & 63;
          if (sel == 0)
            qo[(((size_t)b * H_ + h) * N_ + n) * HD_ + hd] = (bf16)(v * SCALE_);
          else if (sel == 1)
            ko[(((size_t)b * H_ + h) * N_ + n) * HD_ + hd] = (bf16)v;
          else
            vo[(((size_t)b * H_ + h) * HD_ + hd) * VTP_ + n] = (bf16)v;   // transposed
        } else {
          Coutf[(size_t)m * Nn + d] = v;
        }
      }
    }
  }
}

// ---------------- attention: per (qtile, h, b) block, barrier-free, max-free softmax ----------------
#define SW 232   // P row stride (bf16 elems); PV consumes cols 0..223
__global__ __launch_bounds__(256) void attn_kernel(
    const bf16* __restrict__ q, const bf16* __restrict__ k, const bf16* __restrict__ vT_g,
    const bf16* __restrict__ rpbT, bf16* __restrict__ out)
{
  __shared__ __align__(16) bf16 s_lds[64 * SW];   // P tile (each wave owns its 16 rows)

  const int tid = threadIdx.x;
  const int lane = tid & 63, w = tid >> 6;
  const int l15 = lane & 15, quad = lane >> 4;
  const int qt = blockIdx.x, h = blockIdx.y, b = blockIdx.z;
  const size_t bh = ((size_t)b * H_ + h) * N_ * HD_;
  const bf16* qb = q + bh;
  const bf16* kb = k + bh;
  const bf16* vg = vT_g + ((size_t)b * H_ + h) * HD_ * VTP_;

  // zero this wave's P pad cols [208,224)  (QK pass writes cols 0..207)
  if (quad < 2)
    *(uint4*)(&s_lds[(w * 16 + l15) * SW + 208 + quad * 8]) = (uint4){0, 0, 0, 0};

  // ---- fused pass: S = Q K^T + rpb, P = exp(S), rowsum ----
  const int row0 = qt * 64 + w * 16;
  int qm = row0 + l15; if (qm > N_ - 1) qm = N_ - 1;
  bf16x8 aq0 = *(const bf16x8*)(qb + qm * HD_ + quad * 8);
  bf16x8 aq1 = *(const bf16x8*)(qb + qm * HD_ + 32 + quad * 8);

  int rbase = row0 + quad * 4; if (rbase > N_ - 1) rbase = N_ - 1;

  float sum[4] = {0.f, 0.f, 0.f, 0.f};
#pragma unroll
  for (int jt = 0; jt < 13; ++jt) {
    int col = jt * 16 + l15;
    int kn = col; if (kn > N_ - 1) kn = N_ - 1;
    bf16x8 bk0 = *(const bf16x8*)(kb + kn * HD_ + quad * 8);
    bf16x8 bk1 = *(const bf16x8*)(kb + kn * HD_ + 32 + quad * 8);
    bf16x4 rb = *(const bf16x4*)(rpbT + ((size_t)h * N_ + kn) * VTP_ + rbase);
    f32x4 s = {0.f, 0.f, 0.f, 0.f};
    s = __builtin_amdgcn_mfma_f32_16x16x32_bf16(aq0, bk0, s, 0, 0, 0);
    s = __builtin_amdgcn_mfma_f32_16x16x32_bf16(aq1, bk1, s, 0, 0, 0);
#pragma unroll
    for (int r = 0; r < 4; ++r) {
      int row = row0 + quad * 4 + r;
      // scores are O(10); pads get -30000 -> exp underflows to exactly 0
      float sv = (col < N_ && row < N_) ? (s[r] + (float)rb[r]) : NEGI_;
      float p = __expf(sv);
      bf16 pb = (bf16)p;
      s_lds[(w * 16 + quad * 4 + r) * SW + col] = pb;
      sum[r] += (float)pb;
    }
  }

  // prefetch phase-B kk=0 V fragments into the shuffle-latency shadow
  bf16x8 bv0[4];
#pragma unroll
  for (int j2 = 0; j2 < 4; ++j2)
    bv0[j2] = *(const bf16x8*)(vg + (j2 * 16 + l15) * VTP_ + quad * 8);

#pragma unroll
  for (int r = 0; r < 4; ++r) {
    sum[r] += __shfl_xor(sum[r], 1);
    sum[r] += __shfl_xor(sum[r], 2);
    sum[r] += __shfl_xor(sum[r], 4);
    sum[r] += __shfl_xor(sum[r], 8);
  }
  float inv[4];
#pragma unroll
  for (int r = 0; r < 4; ++r) inv[r] = 1.0f / fmaxf(sum[r], 1e-20f);

  // ---- phase B: O = P @ V  (V^T fragments straight from global; pads hit exact-zero P) ----
  f32x4 o[4] = {};
  {
    bf16x8 ap = *(const bf16x8*)(&s_lds[(w * 16 + l15) * SW + quad * 8]);
#pragma unroll
    for (int j2 = 0; j2 < 4; ++j2)
      o[j2] = __builtin_amdgcn_mfma_f32_16x16x32_bf16(ap, bv0[j2], o[j2], 0, 0, 0);
  }
#pragma unroll
  for (int kk = 1; kk < 7; ++kk) {
    bf16x8 ap = *(const bf16x8*)(&s_lds[(w * 16 + l15) * SW + kk * 32 + quad * 8]);
#pragma unroll
    for (int j2 = 0; j2 < 4; ++j2) {
      bf16x8 bv = *(const bf16x8*)(vg + (j2 * 16 + l15) * VTP_ + kk * 32 + quad * 8);
      o[j2] = __builtin_amdgcn_mfma_f32_16x16x32_bf16(ap, bv, o[j2], 0, 0, 0);
    }
  }
#pragma unroll
  for (int j2 = 0; j2 < 4; ++j2) {
#pragma unroll
    for (int r = 0; r < 4; ++r) {
      int row = qt * 64 + w * 16 + quad * 4 + r;
      int hd = j2 * 16 + l15;
      if (row < N_)
        out[((size_t)b * N_ + row) * C_ + h * HD_ + hd] = (bf16)(o[j2][r] * inv[r]);
    }
  }
}

// ---------------- launch ----------------
extern "C" void kernel_launch(void* const* d_in, const int* in_sizes, int n_in,
                              void* d_out, int out_size, void* d_ws, size_t ws_size,
                              hipStream_t stream)
{
  const float* x      = (const float*)d_in[0];
  const float* qkv_w  = (const float*)d_in[1];
  const float* q_bias = (const float*)d_in[2];
  const float* v_bias = (const float*)d_in[3];
  const float* q_la   = (const float*)d_in[4];
  const float* q_lb   = (const float*)d_in[5];
  const float* k_la   = (const float*)d_in[6];
  const float* k_lb   = (const float*)d_in[7];
  const float* v_la   = (const float*)d_in[8];
  const float* v_lb   = (const float*)d_in[9];
  const float* rpt    = (const float*)d_in[10];
  const float* proj_w = (const float*)d_in[11];
  const float* proj_b = (const float*)d_in[12];
  const int*   rpi    = (const int*)d_in[13];
  float* out = (float*)d_out;

  char* ws = (char*)d_ws;
  // layout (16B-aligned); xbf dead after gemm<0>, reused as aout
  bf16*  xbf   = (bf16*)(ws);                         // 19,365,888 B
  bf16*  aout  = (bf16*)(ws);                         // alias
  bf16*  weff  = (bf16*)(ws + 19365888);              //  3,538,944 B
  float* biasf = (float*)(ws + 22904832);             //      9,216 B
  bf16*  pwbf  = (bf16*)(ws + 22914048);              //  1,179,648 B
  bf16*  qbuf  = (bf16*)(ws + 24093696);              // 19,365,888 B
  bf16*  kbuf  = (bf16*)(ws + 43459584);              // 19,365,888 B
  bf16*  vbufT = (bf16*)(ws + 62825472);              // 19,660,800 (+128 slack)
  bf16*  rpbT  = (bf16*)(ws + 82486400);              // 945,600
  // total ws use ≈ 83.4 MB

  prep_kernel<<<13748, 256, 0, stream>>>(
      x, proj_w, qkv_w, q_bias, v_bias, q_la, q_lb, k_la, k_lb, v_la, v_lb,
      rpt, rpi, xbf, pwbf, weff, biasf, rpbT);

  gemm_bt<0><<<dim3(18, 99), 512, 0, stream>>>(
      xbf, weff, biasf, nullptr, M_, 3 * C_, C_, qbuf, kbuf, vbufT);

  attn_kernel<<<dim3(4, H_, B_), 256, 0, stream>>>(qbuf, kbuf, vbufT, rpbT, aout);

  gemm_bt<1><<<dim3(6, 99), 512, 0, stream>>>(
      aout, pwbf, proj_b, out, M_, C_, C_, nullptr, nullptr, nullptr);
}

// Round 6
// 303.610 us; speedup vs baseline: 1.5360x; 1.0033x over previous
//
#include <hip/hip_runtime.h>

typedef __bf16 bf16;
typedef __attribute__((ext_vector_type(8))) __bf16 bf16x8;
typedef __attribute__((ext_vector_type(4))) __bf16 bf16x4;
typedef __attribute__((ext_vector_type(4))) float f32x4;

#define B_    64
#define N_    197
#define C_    768
#define H_    12
#define HD_   64
#define SCALE_ 0.125f
#define NM_   (N_*N_)         // 38809
#define M_    (B_*N_)         // 12608
#define NEGI_ (-30000.0f)
#define VTP_  200             // vbufT / rpbT row pad

#define GLL16(gptr, lptr) \
  __builtin_amdgcn_global_load_lds((const __attribute__((address_space(1))) unsigned int*)(gptr), \
                                   (__attribute__((address_space(3))) unsigned int*)(lptr), 16, 0, 0)

// ---------------- fused prep: cast x/proj_w, W_eff + bias, rpbT ----------------
// blocks [0,5016): cast; [5016,11928): weff; [11928,13748): rpbT
// rpbT layout CHANGED this round: [h][q-row n][k-col m] (+VTP_ pad) — prep write
// becomes unit-stride (was 400B-strided scatter), attn read becomes coalesced.
__global__ __launch_bounds__(256) void prep_kernel(
    const float* __restrict__ x, const float* __restrict__ pw,
    const float* __restrict__ qkv_w, const float* __restrict__ q_bias, const float* __restrict__ v_bias,
    const float* __restrict__ qa, const float* __restrict__ qb,
    const float* __restrict__ ka, const float* __restrict__ kb,
    const float* __restrict__ va, const float* __restrict__ vb,
    const float* __restrict__ table, const int* __restrict__ rpi,
    bf16* __restrict__ xbf, bf16* __restrict__ pwbf,
    bf16* __restrict__ weff, float* __restrict__ biasf, bf16* __restrict__ rpbT)
{
  const int bid = blockIdx.x, tid = threadIdx.x;
  if (bid < 5016) {
    const size_t n1 = (size_t)M_ * C_;   // 9,682,944
    size_t i8 = ((size_t)bid * 256 + tid) * 8;
    const float* src; bf16* dst; size_t off;
    if (i8 < n1) { src = x;  dst = xbf;  off = i8; }
    else         { src = pw; dst = pwbf; off = i8 - n1; }
    float4 f0 = *(const float4*)(src + off);
    float4 f1 = *(const float4*)(src + off + 4);
    bf16x8 v8;
    v8[0] = (bf16)f0.x; v8[1] = (bf16)f0.y; v8[2] = (bf16)f0.z; v8[3] = (bf16)f0.w;
    v8[4] = (bf16)f1.x; v8[5] = (bf16)f1.y; v8[6] = (bf16)f1.z; v8[7] = (bf16)f1.w;
    *(bf16x8*)(dst + off) = v8;
  } else if (bid < 11928) {
    int idx = (bid - 5016) * 256 + tid;          // < 1,769,472 exact
    int d = idx / C_, c = idx - d * C_;
    int sel = d / C_, dd = d - sel * C_;
    const float* a  = (sel == 0) ? qa : (sel == 1) ? ka : va;
    const float* bw = (sel == 0) ? qb : (sel == 1) ? kb : vb;
    float acc = qkv_w[idx];
#pragma unroll
    for (int r = 0; r < 24; ++r)
      acc += bw[dd * 24 + r] * a[r * C_ + c];
    weff[idx] = (bf16)acc;
    if (c == 0)
      biasf[d] = (sel == 0) ? q_bias[dd] : (sel == 2) ? v_bias[dd] : 0.0f;
  } else {
    int idx = (bid - 11928) * 256 + tid;
    if (idx < H_ * NM_) {
      int h = idx / NM_, nm = idx - h * NM_;
      int n = nm / N_, m = nm - n * N_;
      rpbT[((size_t)h * N_ + n) * VTP_ + m] = (bf16)table[rpi[nm] * H_ + h];  // unit-stride write
    }
  }
}

// ---------------- gemm_bt: C[M,Nn] = A[M,K] @ B[Nn,K]^T, bf16 operands ----------------
// Scorecard (gemm<0>): R0 4w/128^2 = 98; 8ph-256^2 = 139; BK64-dbuf = 132; BK32-dbuf = 110;
// LDS-free = 225; R5 8w/128^2 = 92.5 (WIN, 32 wave-slots). R5 showed slot cap reached but
// per-wave LDS/barrier overhead still high (64x32 wave tile: (wM+wN)/(wM*wN)=1/21).
// This round gemm<0> only: BM=256 (256x128 block tile), 8 waves of 64x64 (ratio 1/32,
// barriers/FLOP halved, staged bytes/FLOP 0.75x) at 2 blocks/CU (VGPR ~115 -> 4/SIMD).
// gemm<1> kept at R5-exact (BM=128) for clean attribution.
// MODE 0: scatter q(xSCALE)/k -> [B,H,N,HD]; v -> TRANSPOSED [B,H,HD,VTP_]
// MODE 1: C[m,d] = acc + biasp[d] -> f32 out
template<int MODE, int BM>
__global__ __launch_bounds__(512, (BM == 256) ? 4 : 8) void gemm_bt(
    const bf16* __restrict__ A, const bf16* __restrict__ Bw,
    const float* __restrict__ biasp,
    float* __restrict__ Coutf, int M, int Nn, int K,
    bf16* __restrict__ qo, bf16* __restrict__ ko, bf16* __restrict__ vo)
{
  __shared__ __align__(16) bf16 As[BM * 64];
  __shared__ __align__(16) bf16 Bs[128 * 64];
  const int tid = threadIdx.x;
  const int lane = tid & 63, w = tid >> 6;          // 8 waves
  const int l15 = lane & 15, quad = lane >> 4;
  const int wm = (BM == 256) ? (w & 3) * 64 : (w & 1) * 64;
  const int wn = (BM == 256) ? (w >> 2) * 64 : (w >> 1) * 32;
  constexpr int NF = (BM == 256) ? 4 : 2;           // B-fragments per wave
  const int rowA0 = blockIdx.y * BM;    // M-tile
  const int rowB0 = blockIdx.x * 128;   // N-tile (fastest-varying)

  f32x4 acc[4][NF] = {};

  for (int kt = 0; kt < K; kt += 64) {
#pragma unroll
    for (int i = 0; i < BM / 64; ++i) {            // A: BM x 64 tile
      int lin = i * 512 + tid;
      int r  = lin >> 3;                           // 0..BM-1
      int cb = lin & 7;                            // LDS column block
      int csw = ((cb ^ (r & 7)) << 3);             // swizzled global column (elems)
      int ga = rowA0 + r; if (ga > M - 1) ga = M - 1;
      GLL16(A + (size_t)ga * K + kt + csw, &As[lin * 8]);
    }
#pragma unroll
    for (int i = 0; i < 2; ++i) {                  // B: 128 x 64 tile
      int lin = i * 512 + tid;
      int r  = lin >> 3;
      int cb = lin & 7;
      int csw = ((cb ^ (r & 7)) << 3);
      int gb = rowB0 + r; if (gb > Nn - 1) gb = Nn - 1;
      GLL16(Bw + (size_t)gb * K + kt + csw, &Bs[lin * 8]);
    }
    __syncthreads();
#pragma unroll
    for (int ks = 0; ks < 2; ++ks) {
      const int cb = ks * 4 + quad;                // k-block 0..7
      const int sw = (cb ^ (l15 & 7)) << 3;
      bf16x8 af[4], bfr[NF];
#pragma unroll
      for (int i = 0; i < 4; ++i)
        af[i] = *(const bf16x8*)(&As[(wm + i * 16 + l15) * 64 + sw]);
#pragma unroll
      for (int j = 0; j < NF; ++j)
        bfr[j] = *(const bf16x8*)(&Bs[(wn + j * 16 + l15) * 64 + sw]);
#pragma unroll
      for (int i = 0; i < 4; ++i)
#pragma unroll
        for (int j = 0; j < NF; ++j)
          acc[i][j] = __builtin_amdgcn_mfma_f32_16x16x32_bf16(af[i], bfr[j], acc[i][j], 0, 0, 0);
    }
    __syncthreads();
  }

#pragma unroll
  for (int i = 0; i < 4; ++i) {
#pragma unroll
    for (int j = 0; j < NF; ++j) {
#pragma unroll
      for (int r = 0; r < 4; ++r) {
        int m = rowA0 + wm + i * 16 + quad * 4 + r;
        int d = rowB0 + wn + j * 16 + l15;
        if (m >= M) continue;
        float v = acc[i][j][r] + biasp[d];
        if (MODE == 0) {
          int b = m / N_, n = m - b * N_;
          int sel = d / C_, dd = d - sel * C_;
          int h = dd >> 6, hd = dd & 63;
          if (sel == 0)
            qo[(((size_t)b * H_ + h) * N_ + n) * HD_ + hd] = (bf16)(v * SCALE_);
          else if (sel == 1)
            ko[(((size_t)b * H_ + h) * N_ + n) * HD_ + hd] = (bf16)v;
          else
            vo[(((size_t)b * H_ + h) * HD_ + hd) * VTP_ + n] = (bf16)v;   // transposed
        } else {
          Coutf[(size_t)m * Nn + d] = v;
        }
      }
    }
  }
}

// ---------------- attention: per (qtile, h, b) block, barrier-free, max-free softmax ----------------
#define SW 232   // P row stride (bf16 elems); PV consumes cols 0..223
__global__ __launch_bounds__(256) void attn_kernel(
    const bf16* __restrict__ q, const bf16* __restrict__ k, const bf16* __restrict__ vT_g,
    const bf16* __restrict__ rpbT, bf16* __restrict__ out)
{
  __shared__ __align__(16) bf16 s_lds[64 * SW];   // P tile (each wave owns its 16 rows)

  const int tid = threadIdx.x;
  const int lane = tid & 63, w = tid >> 6;
  const int l15 = lane & 15, quad = lane >> 4;
  const int qt = blockIdx.x, h = blockIdx.y, b = blockIdx.z;
  const size_t bh = ((size_t)b * H_ + h) * N_ * HD_;
  const bf16* qb = q + bh;
  const bf16* kb = k + bh;
  const bf16* vg = vT_g + ((size_t)b * H_ + h) * HD_ * VTP_;

  // zero this wave's P pad cols [208,224)  (QK pass writes cols 0..207)
  if (quad < 2)
    *(uint4*)(&s_lds[(w * 16 + l15) * SW + 208 + quad * 8]) = (uint4){0, 0, 0, 0};

  // ---- fused pass: S = Q K^T + rpb, P = exp(S), rowsum ----
  const int row0 = qt * 64 + w * 16;
  int qm = row0 + l15; if (qm > N_ - 1) qm = N_ - 1;
  bf16x8 aq0 = *(const bf16x8*)(qb + qm * HD_ + quad * 8);
  bf16x8 aq1 = *(const bf16x8*)(qb + qm * HD_ + 32 + quad * 8);

  int rbase = row0 + quad * 4; if (rbase > N_ - 1) rbase = N_ - 1;

  float sum[4] = {0.f, 0.f, 0.f, 0.f};
#pragma unroll
  for (int jt = 0; jt < 13; ++jt) {
    int col = jt * 16 + l15;
    int kn = col; if (kn > N_ - 1) kn = N_ - 1;
    bf16x8 bk0 = *(const bf16x8*)(kb + kn * HD_ + quad * 8);
    bf16x8 bk1 = *(const bf16x8*)(kb + kn * HD_ + 32 + quad * 8);
    // rpbT now [h][q-row][k-col]: 4 coalesced scalar loads (lane -> kn contiguous),
    // replaces the 400B-strided bf16x4 gather (~64 lines/instr -> ~4)
    float rbv[4];
#pragma unroll
    for (int r2 = 0; r2 < 4; ++r2) {
      int rn = rbase + r2; if (rn > N_ - 1) rn = N_ - 1;   // clamped lanes are masked below
      rbv[r2] = (float)rpbT[((size_t)h * N_ + rn) * VTP_ + kn];
    }
    f32x4 s = {0.f, 0.f, 0.f, 0.f};
    s = __builtin_amdgcn_mfma_f32_16x16x32_bf16(aq0, bk0, s, 0, 0, 0);
    s = __builtin_amdgcn_mfma_f32_16x16x32_bf16(aq1, bk1, s, 0, 0, 0);
#pragma unroll
    for (int r = 0; r < 4; ++r) {
      int row = row0 + quad * 4 + r;
      // scores are O(10); pads get -30000 -> exp underflows to exactly 0
      float sv = (col < N_ && row < N_) ? (s[r] + rbv[r]) : NEGI_;
      float p = __expf(sv);
      bf16 pb = (bf16)p;
      s_lds[(w * 16 + quad * 4 + r) * SW + col] = pb;
      sum[r] += (float)pb;
    }
  }

  // prefetch phase-B kk=0 V fragments into the shuffle-latency shadow
  bf16x8 bv0[4];
#pragma unroll
  for (int j2 = 0; j2 < 4; ++j2)
    bv0[j2] = *(const bf16x8*)(vg + (j2 * 16 + l15) * VTP_ + quad * 8);

#pragma unroll
  for (int r = 0; r < 4; ++r) {
    sum[r] += __shfl_xor(sum[r], 1);
    sum[r] += __shfl_xor(sum[r], 2);
    sum[r] += __shfl_xor(sum[r], 4);
    sum[r] += __shfl_xor(sum[r], 8);
  }
  float inv[4];
#pragma unroll
  for (int r = 0; r < 4; ++r) inv[r] = 1.0f / fmaxf(sum[r], 1e-20f);

  // ---- phase B: O = P @ V  (V^T fragments straight from global; pads hit exact-zero P) ----
  f32x4 o[4] = {};
  {
    bf16x8 ap = *(const bf16x8*)(&s_lds[(w * 16 + l15) * SW + quad * 8]);
#pragma unroll
    for (int j2 = 0; j2 < 4; ++j2)
      o[j2] = __builtin_amdgcn_mfma_f32_16x16x32_bf16(ap, bv0[j2], o[j2], 0, 0, 0);
  }
#pragma unroll
  for (int kk = 1; kk < 7; ++kk) {
    bf16x8 ap = *(const bf16x8*)(&s_lds[(w * 16 + l15) * SW + kk * 32 + quad * 8]);
#pragma unroll
    for (int j2 = 0; j2 < 4; ++j2) {
      bf16x8 bv = *(const bf16x8*)(vg + (j2 * 16 + l15) * VTP_ + kk * 32 + quad * 8);
      o[j2] = __builtin_amdgcn_mfma_f32_16x16x32_bf16(ap, bv, o[j2], 0, 0, 0);
    }
  }
#pragma unroll
  for (int j2 = 0; j2 < 4; ++j2) {
#pragma unroll
    for (int r = 0; r < 4; ++r) {
      int row = qt * 64 + w * 16 + quad * 4 + r;
      int hd = j2 * 16 + l15;
      if (row < N_)
        out[((size_t)b * N_ + row) * C_ + h * HD_ + hd] = (bf16)(o[j2][r] * inv[r]);
    }
  }
}

// ---------------- launch ----------------
extern "C" void kernel_launch(void* const* d_in, const int* in_sizes, int n_in,
                              void* d_out, int out_size, void* d_ws, size_t ws_size,
                              hipStream_t stream)
{
  const float* x      = (const float*)d_in[0];
  const float* qkv_w  = (const float*)d_in[1];
  const float* q_bias = (const float*)d_in[2];
  const float* v_bias = (const float*)d_in[3];
  const float* q_la   = (const float*)d_in[4];
  const float* q_lb   = (const float*)d_in[5];
  const float* k_la   = (const float*)d_in[6];
  const float* k_lb   = (const float*)d_in[7];
  const float* v_la   = (const float*)d_in[8];
  const float* v_lb   = (const float*)d_in[9];
  const float* rpt    = (const float*)d_in[10];
  const float* proj_w = (const float*)d_in[11];
  const float* proj_b = (const float*)d_in[12];
  const int*   rpi    = (const int*)d_in[13];
  float* out = (float*)d_out;

  char* ws = (char*)d_ws;
  // layout (16B-aligned); xbf dead after gemm<0>, reused as aout
  bf16*  xbf   = (bf16*)(ws);                         // 19,365,888 B
  bf16*  aout  = (bf16*)(ws);                         // alias
  bf16*  weff  = (bf16*)(ws + 19365888);              //  3,538,944 B
  float* biasf = (float*)(ws + 22904832);             //      9,216 B
  bf16*  pwbf  = (bf16*)(ws + 22914048);              //  1,179,648 B
  bf16*  qbuf  = (bf16*)(ws + 24093696);              // 19,365,888 B
  bf16*  kbuf  = (bf16*)(ws + 43459584);              // 19,365,888 B
  bf16*  vbufT = (bf16*)(ws + 62825472);              // 19,660,800 (+128 slack)
  bf16*  rpbT  = (bf16*)(ws + 82486400);              // 945,600
  // total ws use ≈ 83.4 MB

  prep_kernel<<<13748, 256, 0, stream>>>(
      x, proj_w, qkv_w, q_bias, v_bias, q_la, q_lb, k_la, k_lb, v_la, v_lb,
      rpt, rpi, xbf, pwbf, weff, biasf, rpbT);

  // BM=256: grid (18 N-tiles, 50 M-tiles) = 900 blocks, 48KB LDS, 2 blocks/CU
  gemm_bt<0, 256><<<dim3(18, 50), 512, 0, stream>>>(
      xbf, weff, biasf, nullptr, M_, 3 * C_, C_, qbuf, kbuf, vbufT);

  attn_kernel<<<dim3(4, H_, B_), 256, 0, stream>>>(qbuf, kbuf, vbufT, rpbT, aout);

  // R5-exact structure for attribution
  gemm_bt<1, 128><<<dim3(6, 99), 512, 0, stream>>>(
      aout, pwbf, proj_b, out, M_, C_, C_, nullptr, nullptr, nullptr);
}

// Round 7
// 282.535 us; speedup vs baseline: 1.6506x; 1.0746x over previous
//
#include <hip/hip_runtime.h>

typedef __bf16 bf16;
typedef __attribute__((ext_vector_type(8))) __bf16 bf16x8;
typedef __attribute__((ext_vector_type(4))) __bf16 bf16x4;
typedef __attribute__((ext_vector_type(4))) float f32x4;

#define B_    64
#define N_    197
#define C_    768
#define H_    12
#define HD_   64
#define SCALE_ 0.125f
#define NM_   (N_*N_)         // 38809
#define M_    (B_*N_)         // 12608
#define NEGI_ (-30000.0f)
#define VTP_  200             // vbufT / rpbT row pad

#define GLL16(gptr, lptr) \
  __builtin_amdgcn_global_load_lds((const __attribute__((address_space(1))) unsigned int*)(gptr), \
                                   (__attribute__((address_space(3))) unsigned int*)(lptr), 16, 0, 0)

// ---------------- fused prep: cast x/proj_w, W_eff + bias, rpbT ----------------
// blocks [0,5016): cast; [5016,11928): weff; [11928,13748): rpbT
// rpbT layout [h][q-row n][k-col m] (+VTP_ pad): unit-stride prep write,
// coalesced attn read (R6 win, ~9us on attn+prep).
__global__ __launch_bounds__(256) void prep_kernel(
    const float* __restrict__ x, const float* __restrict__ pw,
    const float* __restrict__ qkv_w, const float* __restrict__ q_bias, const float* __restrict__ v_bias,
    const float* __restrict__ qa, const float* __restrict__ qb,
    const float* __restrict__ ka, const float* __restrict__ kb,
    const float* __restrict__ va, const float* __restrict__ vb,
    const float* __restrict__ table, const int* __restrict__ rpi,
    bf16* __restrict__ xbf, bf16* __restrict__ pwbf,
    bf16* __restrict__ weff, float* __restrict__ biasf, bf16* __restrict__ rpbT)
{
  const int bid = blockIdx.x, tid = threadIdx.x;
  if (bid < 5016) {
    const size_t n1 = (size_t)M_ * C_;   // 9,682,944
    size_t i8 = ((size_t)bid * 256 + tid) * 8;
    const float* src; bf16* dst; size_t off;
    if (i8 < n1) { src = x;  dst = xbf;  off = i8; }
    else         { src = pw; dst = pwbf; off = i8 - n1; }
    float4 f0 = *(const float4*)(src + off);
    float4 f1 = *(const float4*)(src + off + 4);
    bf16x8 v8;
    v8[0] = (bf16)f0.x; v8[1] = (bf16)f0.y; v8[2] = (bf16)f0.z; v8[3] = (bf16)f0.w;
    v8[4] = (bf16)f1.x; v8[5] = (bf16)f1.y; v8[6] = (bf16)f1.z; v8[7] = (bf16)f1.w;
    *(bf16x8*)(dst + off) = v8;
  } else if (bid < 11928) {
    int idx = (bid - 5016) * 256 + tid;          // < 1,769,472 exact
    int d = idx / C_, c = idx - d * C_;
    int sel = d / C_, dd = d - sel * C_;
    const float* a  = (sel == 0) ? qa : (sel == 1) ? ka : va;
    const float* bw = (sel == 0) ? qb : (sel == 1) ? kb : vb;
    float acc = qkv_w[idx];
#pragma unroll
    for (int r = 0; r < 24; ++r)
      acc += bw[dd * 24 + r] * a[r * C_ + c];
    weff[idx] = (bf16)acc;
    if (c == 0)
      biasf[d] = (sel == 0) ? q_bias[dd] : (sel == 2) ? v_bias[dd] : 0.0f;
  } else {
    int idx = (bid - 11928) * 256 + tid;
    if (idx < H_ * NM_) {
      int h = idx / NM_, nm = idx - h * NM_;
      int n = nm / N_, m = nm - n * N_;
      rpbT[((size_t)h * N_ + n) * VTP_ + m] = (bf16)table[rpi[nm] * H_ + h];  // unit-stride write
    }
  }
}

// ---------------- gemm_bt: C[M,Nn] = A[M,K] @ B[Nn,K]^T, bf16 operands ----------------
// Scorecard (gemm<0>): R0 4w/128^2 = 98; 8ph-256^2 = 139; BK64-dbuf = 132; BK32-dbuf = 110;
// LDS-free = 225; R5 8w/128^2 = 92.5 (WIN, 32 waves/CU); R6 8w/256x128 = 101 (16 waves/CU).
// Law (3x confirmed): wave-slot occupancy beats per-wave efficiency at this shape.
// This round: R5-exact structure + packed bf16x4 v-stores in the epilogue
// (v's 4 r-values are consecutive n for fixed (b,h,hd) row -> one 8B store instead of
// four 2B scatters; attacks the ~68MB RFO excess in FETCH_SIZE).
// MODE 0: scatter q(xSCALE)/k -> [B,H,N,HD]; v -> TRANSPOSED [B,H,HD,VTP_]
// MODE 1: C[m,d] = acc + biasp[d] -> f32 out
template<int MODE, int BM>
__global__ __launch_bounds__(512, 8) void gemm_bt(
    const bf16* __restrict__ A, const bf16* __restrict__ Bw,
    const float* __restrict__ biasp,
    float* __restrict__ Coutf, int M, int Nn, int K,
    bf16* __restrict__ qo, bf16* __restrict__ ko, bf16* __restrict__ vo)
{
  __shared__ __align__(16) bf16 As[BM * 64];
  __shared__ __align__(16) bf16 Bs[128 * 64];
  const int tid = threadIdx.x;
  const int lane = tid & 63, w = tid >> 6;          // 8 waves
  const int l15 = lane & 15, quad = lane >> 4;
  const int wm = (w & 1) * 64;                      // M half (64 rows)
  const int wn = (w >> 1) * 32;                     // N quarter (32 cols)
  constexpr int NF = 2;                             // B-fragments per wave
  const int rowA0 = blockIdx.y * BM;    // M-tile
  const int rowB0 = blockIdx.x * 128;   // N-tile (fastest-varying)

  f32x4 acc[4][NF] = {};

  for (int kt = 0; kt < K; kt += 64) {
#pragma unroll
    for (int i = 0; i < BM / 64; ++i) {            // A: BM x 64 tile
      int lin = i * 512 + tid;
      int r  = lin >> 3;                           // 0..BM-1
      int cb = lin & 7;                            // LDS column block
      int csw = ((cb ^ (r & 7)) << 3);             // swizzled global column (elems)
      int ga = rowA0 + r; if (ga > M - 1) ga = M - 1;
      GLL16(A + (size_t)ga * K + kt + csw, &As[lin * 8]);
    }
#pragma unroll
    for (int i = 0; i < 2; ++i) {                  // B: 128 x 64 tile
      int lin = i * 512 + tid;
      int r  = lin >> 3;
      int cb = lin & 7;
      int csw = ((cb ^ (r & 7)) << 3);
      int gb = rowB0 + r; if (gb > Nn - 1) gb = Nn - 1;
      GLL16(Bw + (size_t)gb * K + kt + csw, &Bs[lin * 8]);
    }
    __syncthreads();
#pragma unroll
    for (int ks = 0; ks < 2; ++ks) {
      const int cb = ks * 4 + quad;                // k-block 0..7
      const int sw = (cb ^ (l15 & 7)) << 3;
      bf16x8 af[4], bfr[NF];
#pragma unroll
      for (int i = 0; i < 4; ++i)
        af[i] = *(const bf16x8*)(&As[(wm + i * 16 + l15) * 64 + sw]);
#pragma unroll
      for (int j = 0; j < NF; ++j)
        bfr[j] = *(const bf16x8*)(&Bs[(wn + j * 16 + l15) * 64 + sw]);
#pragma unroll
      for (int i = 0; i < 4; ++i)
#pragma unroll
        for (int j = 0; j < NF; ++j)
          acc[i][j] = __builtin_amdgcn_mfma_f32_16x16x32_bf16(af[i], bfr[j], acc[i][j], 0, 0, 0);
    }
    __syncthreads();
  }

#pragma unroll
  for (int i = 0; i < 4; ++i) {
#pragma unroll
    for (int j = 0; j < NF; ++j) {
      const int m0 = rowA0 + wm + i * 16 + quad * 4;
      const int d  = rowB0 + wn + j * 16 + l15;
      const float bias = biasp[d];
      if (MODE == 0) {
        const int sel = d / C_, dd = d - sel * C_;
        const int h = dd >> 6, hd = dd & 63;
        if (sel == 2) {
          // v transposed: lane's 4 r-values = consecutive n for fixed (b,h,hd) row
          int b0 = m0 / N_, n0 = m0 - b0 * N_;
          if (m0 + 3 < M && n0 + 3 < N_) {
            bf16x4 pv;
#pragma unroll
            for (int r = 0; r < 4; ++r) pv[r] = (bf16)(acc[i][j][r] + bias);
            *(bf16x4*)(vo + (((size_t)b0 * H_ + h) * HD_ + hd) * VTP_ + n0) = pv;
          } else {
#pragma unroll
            for (int r = 0; r < 4; ++r) {
              int m = m0 + r; if (m >= M) continue;
              int b = m / N_, n = m - b * N_;
              vo[(((size_t)b * H_ + h) * HD_ + hd) * VTP_ + n] = (bf16)(acc[i][j][r] + bias);
            }
          }
        } else {
#pragma unroll
          for (int r = 0; r < 4; ++r) {
            int m = m0 + r; if (m >= M) continue;
            int b = m / N_, n = m - b * N_;
            float v = acc[i][j][r] + bias;
            if (sel == 0)
              qo[(((size_t)b * H_ + h) * N_ + n) * HD_ + hd] = (bf16)(v * SCALE_);
            else
              ko[(((size_t)b * H_ + h) * N_ + n) * HD_ + hd] = (bf16)v;
          }
        }
      } else {
#pragma unroll
        for (int r = 0; r < 4; ++r) {
          int m = m0 + r; if (m >= M) continue;
          Coutf[(size_t)m * Nn + d] = acc[i][j][r] + bias;
        }
      }
    }
  }
}

// ---------------- attention: per (qtile, h, b) block, barrier-free, max-free softmax ----------------
#define SW 232   // P row stride (bf16 elems); PV consumes cols 0..223
__global__ __launch_bounds__(256) void attn_kernel(
    const bf16* __restrict__ q, const bf16* __restrict__ k, const bf16* __restrict__ vT_g,
    const bf16* __restrict__ rpbT, bf16* __restrict__ out)
{
  __shared__ __align__(16) bf16 s_lds[64 * SW];   // P tile (each wave owns its 16 rows)

  const int tid = threadIdx.x;
  const int lane = tid & 63, w = tid >> 6;
  const int l15 = lane & 15, quad = lane >> 4;
  const int qt = blockIdx.x, h = blockIdx.y, b = blockIdx.z;
  const size_t bh = ((size_t)b * H_ + h) * N_ * HD_;
  const bf16* qb = q + bh;
  const bf16* kb = k + bh;
  const bf16* vg = vT_g + ((size_t)b * H_ + h) * HD_ * VTP_;

  // zero this wave's P pad cols [208,224)  (QK pass writes cols 0..207)
  if (quad < 2)
    *(uint4*)(&s_lds[(w * 16 + l15) * SW + 208 + quad * 8]) = (uint4){0, 0, 0, 0};

  // ---- fused pass: S = Q K^T + rpb, P = exp(S), rowsum ----
  const int row0 = qt * 64 + w * 16;
  int qm = row0 + l15; if (qm > N_ - 1) qm = N_ - 1;
  bf16x8 aq0 = *(const bf16x8*)(qb + qm * HD_ + quad * 8);
  bf16x8 aq1 = *(const bf16x8*)(qb + qm * HD_ + 32 + quad * 8);

  int rbase = row0 + quad * 4; if (rbase > N_ - 1) rbase = N_ - 1;

  float sum[4] = {0.f, 0.f, 0.f, 0.f};
#pragma unroll
  for (int jt = 0; jt < 13; ++jt) {
    int col = jt * 16 + l15;
    int kn = col; if (kn > N_ - 1) kn = N_ - 1;
    bf16x8 bk0 = *(const bf16x8*)(kb + kn * HD_ + quad * 8);
    bf16x8 bk1 = *(const bf16x8*)(kb + kn * HD_ + 32 + quad * 8);
    // rpbT [h][q-row][k-col]: 4 coalesced scalar loads (lane -> kn contiguous)
    float rbv[4];
#pragma unroll
    for (int r2 = 0; r2 < 4; ++r2) {
      int rn = rbase + r2; if (rn > N_ - 1) rn = N_ - 1;   // clamped lanes are masked below
      rbv[r2] = (float)rpbT[((size_t)h * N_ + rn) * VTP_ + kn];
    }
    f32x4 s = {0.f, 0.f, 0.f, 0.f};
    s = __builtin_amdgcn_mfma_f32_16x16x32_bf16(aq0, bk0, s, 0, 0, 0);
    s = __builtin_amdgcn_mfma_f32_16x16x32_bf16(aq1, bk1, s, 0, 0, 0);
#pragma unroll
    for (int r = 0; r < 4; ++r) {
      int row = row0 + quad * 4 + r;
      // scores are O(10); pads get -30000 -> exp underflows to exactly 0
      float sv = (col < N_ && row < N_) ? (s[r] + rbv[r]) : NEGI_;
      float p = __expf(sv);
      bf16 pb = (bf16)p;
      s_lds[(w * 16 + quad * 4 + r) * SW + col] = pb;
      sum[r] += (float)pb;
    }
  }

  // prefetch phase-B kk=0 V fragments into the shuffle-latency shadow
  bf16x8 bv0[4];
#pragma unroll
  for (int j2 = 0; j2 < 4; ++j2)
    bv0[j2] = *(const bf16x8*)(vg + (j2 * 16 + l15) * VTP_ + quad * 8);

#pragma unroll
  for (int r = 0; r < 4; ++r) {
    sum[r] += __shfl_xor(sum[r], 1);
    sum[r] += __shfl_xor(sum[r], 2);
    sum[r] += __shfl_xor(sum[r], 4);
    sum[r] += __shfl_xor(sum[r], 8);
  }
  float inv[4];
#pragma unroll
  for (int r = 0; r < 4; ++r) inv[r] = 1.0f / fmaxf(sum[r], 1e-20f);

  // ---- phase B: O = P @ V  (V^T fragments straight from global; pads hit exact-zero P) ----
  f32x4 o[4] = {};
  {
    bf16x8 ap = *(const bf16x8*)(&s_lds[(w * 16 + l15) * SW + quad * 8]);
#pragma unroll
    for (int j2 = 0; j2 < 4; ++j2)
      o[j2] = __builtin_amdgcn_mfma_f32_16x16x32_bf16(ap, bv0[j2], o[j2], 0, 0, 0);
  }
#pragma unroll
  for (int kk = 1; kk < 7; ++kk) {
    bf16x8 ap = *(const bf16x8*)(&s_lds[(w * 16 + l15) * SW + kk * 32 + quad * 8]);
#pragma unroll
    for (int j2 = 0; j2 < 4; ++j2) {
      bf16x8 bv = *(const bf16x8*)(vg + (j2 * 16 + l15) * VTP_ + kk * 32 + quad * 8);
      o[j2] = __builtin_amdgcn_mfma_f32_16x16x32_bf16(ap, bv, o[j2], 0, 0, 0);
    }
  }
#pragma unroll
  for (int j2 = 0; j2 < 4; ++j2) {
#pragma unroll
    for (int r = 0; r < 4; ++r) {
      int row = qt * 64 + w * 16 + quad * 4 + r;
      int hd = j2 * 16 + l15;
      if (row < N_)
        out[((size_t)b * N_ + row) * C_ + h * HD_ + hd] = (bf16)(o[j2][r] * inv[r]);
    }
  }
}

// ---------------- launch ----------------
extern "C" void kernel_launch(void* const* d_in, const int* in_sizes, int n_in,
                              void* d_out, int out_size, void* d_ws, size_t ws_size,
                              hipStream_t stream)
{
  const float* x      = (const float*)d_in[0];
  const float* qkv_w  = (const float*)d_in[1];
  const float* q_bias = (const float*)d_in[2];
  const float* v_bias = (const float*)d_in[3];
  const float* q_la   = (const float*)d_in[4];
  const float* q_lb   = (const float*)d_in[5];
  const float* k_la   = (const float*)d_in[6];
  const float* k_lb   = (const float*)d_in[7];
  const float* v_la   = (const float*)d_in[8];
  const float* v_lb   = (const float*)d_in[9];
  const float* rpt    = (const float*)d_in[10];
  const float* proj_w = (const float*)d_in[11];
  const float* proj_b = (const float*)d_in[12];
  const int*   rpi    = (const int*)d_in[13];
  float* out = (float*)d_out;

  char* ws = (char*)d_ws;
  // layout (16B-aligned); xbf dead after gemm<0>, reused as aout
  bf16*  xbf   = (bf16*)(ws);                         // 19,365,888 B
  bf16*  aout  = (bf16*)(ws);                         // alias
  bf16*  weff  = (bf16*)(ws + 19365888);              //  3,538,944 B
  float* biasf = (float*)(ws + 22904832);             //      9,216 B
  bf16*  pwbf  = (bf16*)(ws + 22914048);              //  1,179,648 B
  bf16*  qbuf  = (bf16*)(ws + 24093696);              // 19,365,888 B
  bf16*  kbuf  = (bf16*)(ws + 43459584);              // 19,365,888 B
  bf16*  vbufT = (bf16*)(ws + 62825472);              // 19,660,800 (+128 slack)
  bf16*  rpbT  = (bf16*)(ws + 82486400);              // 945,600
  // total ws use ≈ 83.4 MB

  prep_kernel<<<13748, 256, 0, stream>>>(
      x, proj_w, qkv_w, q_bias, v_bias, q_la, q_lb, k_la, k_lb, v_la, v_lb,
      rpt, rpi, xbf, pwbf, weff, biasf, rpbT);

  // R5-exact winner: BM=128, 8 waves, 32 KB LDS, 4 blocks/CU -> 32 waves/CU
  gemm_bt<0, 128><<<dim3(18, 99), 512, 0, stream>>>(
      xbf, weff, biasf, nullptr, M_, 3 * C_, C_, qbuf, kbuf, vbufT);

  attn_kernel<<<dim3(4, H_, B_), 256, 0, stream>>>(qbuf, kbuf, vbufT, rpbT, aout);

  gemm_bt<1, 128><<<dim3(6, 99), 512, 0, stream>>>(
      aout, pwbf, proj_b, out, M_, C_, C_, nullptr, nullptr, nullptr);
}

// Round 8
// 281.206 us; speedup vs baseline: 1.6584x; 1.0047x over previous
//
#include <hip/hip_runtime.h>

typedef __bf16 bf16;
typedef __attribute__((ext_vector_type(8))) __bf16 bf16x8;
typedef __attribute__((ext_vector_type(4))) __bf16 bf16x4;
typedef __attribute__((ext_vector_type(4))) float f32x4;

#define B_    64
#define N_    197
#define C_    768
#define H_    12
#define HD_   64
#define SCALE_ 0.125f
#define NM_   (N_*N_)         // 38809
#define M_    (B_*N_)         // 12608
#define NEGI_ (-30000.0f)
#define VTP_  200             // vbufT / rpbT row pad

#define GLL16(gptr, lptr) \
  __builtin_amdgcn_global_load_lds((const __attribute__((address_space(1))) unsigned int*)(gptr), \
                                   (__attribute__((address_space(3))) unsigned int*)(lptr), 16, 0, 0)

// ---------------- fused prep: cast x/proj_w, W_eff + bias, rpbT ----------------
// blocks [0,5016): cast; [5016,11928): weff; [11928,13748): rpbT
// rpbT layout [h][q-row n][k-col m] (+VTP_ pad): unit-stride prep write,
// coalesced attn read (R6 win).
__global__ __launch_bounds__(256) void prep_kernel(
    const float* __restrict__ x, const float* __restrict__ pw,
    const float* __restrict__ qkv_w, const float* __restrict__ q_bias, const float* __restrict__ v_bias,
    const float* __restrict__ qa, const float* __restrict__ qb,
    const float* __restrict__ ka, const float* __restrict__ kb,
    const float* __restrict__ va, const float* __restrict__ vb,
    const float* __restrict__ table, const int* __restrict__ rpi,
    bf16* __restrict__ xbf, bf16* __restrict__ pwbf,
    bf16* __restrict__ weff, float* __restrict__ biasf, bf16* __restrict__ rpbT)
{
  const int bid = blockIdx.x, tid = threadIdx.x;
  if (bid < 5016) {
    const size_t n1 = (size_t)M_ * C_;   // 9,682,944
    size_t i8 = ((size_t)bid * 256 + tid) * 8;
    const float* src; bf16* dst; size_t off;
    if (i8 < n1) { src = x;  dst = xbf;  off = i8; }
    else         { src = pw; dst = pwbf; off = i8 - n1; }
    float4 f0 = *(const float4*)(src + off);
    float4 f1 = *(const float4*)(src + off + 4);
    bf16x8 v8;
    v8[0] = (bf16)f0.x; v8[1] = (bf16)f0.y; v8[2] = (bf16)f0.z; v8[3] = (bf16)f0.w;
    v8[4] = (bf16)f1.x; v8[5] = (bf16)f1.y; v8[6] = (bf16)f1.z; v8[7] = (bf16)f1.w;
    *(bf16x8*)(dst + off) = v8;
  } else if (bid < 11928) {
    int idx = (bid - 5016) * 256 + tid;          // < 1,769,472 exact
    int d = idx / C_, c = idx - d * C_;
    int sel = d / C_, dd = d - sel * C_;
    const float* a  = (sel == 0) ? qa : (sel == 1) ? ka : va;
    const float* bw = (sel == 0) ? qb : (sel == 1) ? kb : vb;
    float acc = qkv_w[idx];
#pragma unroll
    for (int r = 0; r < 24; ++r)
      acc += bw[dd * 24 + r] * a[r * C_ + c];
    weff[idx] = (bf16)acc;
    if (c == 0)
      biasf[d] = (sel == 0) ? q_bias[dd] : (sel == 2) ? v_bias[dd] : 0.0f;
  } else {
    int idx = (bid - 11928) * 256 + tid;
    if (idx < H_ * NM_) {
      int h = idx / NM_, nm = idx - h * NM_;
      int n = nm / N_, m = nm - n * N_;
      rpbT[((size_t)h * N_ + n) * VTP_ + m] = (bf16)table[rpi[nm] * H_ + h];  // unit-stride write
    }
  }
}

// ---------------- gemm_bt: C[M,Nn] = A[M,K] @ B[Nn,K]^T, bf16 operands ----------------
// R7 winner, UNTOUCHED: BM=128, 8 waves, 32KB LDS, 32 waves/CU; packed bf16x4 v-stores
// (RFO fix was worth >=25us on gemm<0>).
// MODE 0: scatter q(xSCALE)/k -> [B,H,N,HD]; v -> TRANSPOSED [B,H,HD,VTP_]
// MODE 1: C[m,d] = acc + biasp[d] -> f32 out
template<int MODE, int BM>
__global__ __launch_bounds__(512, 8) void gemm_bt(
    const bf16* __restrict__ A, const bf16* __restrict__ Bw,
    const float* __restrict__ biasp,
    float* __restrict__ Coutf, int M, int Nn, int K,
    bf16* __restrict__ qo, bf16* __restrict__ ko, bf16* __restrict__ vo)
{
  __shared__ __align__(16) bf16 As[BM * 64];
  __shared__ __align__(16) bf16 Bs[128 * 64];
  const int tid = threadIdx.x;
  const int lane = tid & 63, w = tid >> 6;          // 8 waves
  const int l15 = lane & 15, quad = lane >> 4;
  const int wm = (w & 1) * 64;                      // M half (64 rows)
  const int wn = (w >> 1) * 32;                     // N quarter (32 cols)
  constexpr int NF = 2;                             // B-fragments per wave
  const int rowA0 = blockIdx.y * BM;    // M-tile
  const int rowB0 = blockIdx.x * 128;   // N-tile (fastest-varying)

  f32x4 acc[4][NF] = {};

  for (int kt = 0; kt < K; kt += 64) {
#pragma unroll
    for (int i = 0; i < BM / 64; ++i) {            // A: BM x 64 tile
      int lin = i * 512 + tid;
      int r  = lin >> 3;                           // 0..BM-1
      int cb = lin & 7;                            // LDS column block
      int csw = ((cb ^ (r & 7)) << 3);             // swizzled global column (elems)
      int ga = rowA0 + r; if (ga > M - 1) ga = M - 1;
      GLL16(A + (size_t)ga * K + kt + csw, &As[lin * 8]);
    }
#pragma unroll
    for (int i = 0; i < 2; ++i) {                  // B: 128 x 64 tile
      int lin = i * 512 + tid;
      int r  = lin >> 3;
      int cb = lin & 7;
      int csw = ((cb ^ (r & 7)) << 3);
      int gb = rowB0 + r; if (gb > Nn - 1) gb = Nn - 1;
      GLL16(Bw + (size_t)gb * K + kt + csw, &Bs[lin * 8]);
    }
    __syncthreads();
#pragma unroll
    for (int ks = 0; ks < 2; ++ks) {
      const int cb = ks * 4 + quad;                // k-block 0..7
      const int sw = (cb ^ (l15 & 7)) << 3;
      bf16x8 af[4], bfr[NF];
#pragma unroll
      for (int i = 0; i < 4; ++i)
        af[i] = *(const bf16x8*)(&As[(wm + i * 16 + l15) * 64 + sw]);
#pragma unroll
      for (int j = 0; j < NF; ++j)
        bfr[j] = *(const bf16x8*)(&Bs[(wn + j * 16 + l15) * 64 + sw]);
#pragma unroll
      for (int i = 0; i < 4; ++i)
#pragma unroll
        for (int j = 0; j < NF; ++j)
          acc[i][j] = __builtin_amdgcn_mfma_f32_16x16x32_bf16(af[i], bfr[j], acc[i][j], 0, 0, 0);
    }
    __syncthreads();
  }

#pragma unroll
  for (int i = 0; i < 4; ++i) {
#pragma unroll
    for (int j = 0; j < NF; ++j) {
      const int m0 = rowA0 + wm + i * 16 + quad * 4;
      const int d  = rowB0 + wn + j * 16 + l15;
      const float bias = biasp[d];
      if (MODE == 0) {
        const int sel = d / C_, dd = d - sel * C_;
        const int h = dd >> 6, hd = dd & 63;
        if (sel == 2) {
          // v transposed: lane's 4 r-values = consecutive n for fixed (b,h,hd) row
          int b0 = m0 / N_, n0 = m0 - b0 * N_;
          if (m0 + 3 < M && n0 + 3 < N_) {
            bf16x4 pv;
#pragma unroll
            for (int r = 0; r < 4; ++r) pv[r] = (bf16)(acc[i][j][r] + bias);
            *(bf16x4*)(vo + (((size_t)b0 * H_ + h) * HD_ + hd) * VTP_ + n0) = pv;
          } else {
#pragma unroll
            for (int r = 0; r < 4; ++r) {
              int m = m0 + r; if (m >= M) continue;
              int b = m / N_, n = m - b * N_;
              vo[(((size_t)b * H_ + h) * HD_ + hd) * VTP_ + n] = (bf16)(acc[i][j][r] + bias);
            }
          }
        } else {
#pragma unroll
          for (int r = 0; r < 4; ++r) {
            int m = m0 + r; if (m >= M) continue;
            int b = m / N_, n = m - b * N_;
            float v = acc[i][j][r] + bias;
            if (sel == 0)
              qo[(((size_t)b * H_ + h) * N_ + n) * HD_ + hd] = (bf16)(v * SCALE_);
            else
              ko[(((size_t)b * H_ + h) * N_ + n) * HD_ + hd] = (bf16)v;
          }
        }
      } else {
#pragma unroll
        for (int r = 0; r < 4; ++r) {
          int m = m0 + r; if (m >= M) continue;
          Coutf[(size_t)m * Nn + d] = acc[i][j][r] + bias;
        }
      }
    }
  }
}

// ---------------- attention: barrier-free, max-free softmax ----------------
// R8 changes (attn was top dispatch, 67.8us, all pipes idle = latency-bound):
// 1) XCD-chunked bijective swizzle: flat grid 3072 = 8*384; wg=(lid&7)*384+(lid>>3).
//    The 4 qt-blocks sharing a (h,b) K/V pair land on ONE XCD's L2 (round-robin
//    dispatch put them on 4 different XCDs -> 86MB FETCH vs ~58MB minimum).
// 2) 2-deep K-load pipeline: issue jt+1's K fragments before jt's MFMA/exp chain
//    (compile-time slot index, rule #20 safe; +8 VGPR, LDS still the occupancy cap).
#define SW 232   // P row stride (bf16 elems); PV consumes cols 0..223
__global__ __launch_bounds__(256) void attn_kernel(
    const bf16* __restrict__ q, const bf16* __restrict__ k, const bf16* __restrict__ vT_g,
    const bf16* __restrict__ rpbT, bf16* __restrict__ out)
{
  __shared__ __align__(16) bf16 s_lds[64 * SW];   // P tile (each wave owns its 16 rows)

  const int tid = threadIdx.x;
  const int lane = tid & 63, w = tid >> 6;
  const int l15 = lane & 15, quad = lane >> 4;
  // XCD-chunked bijection (3072 = 8 XCDs x 384): contiguous wg-chunk per XCD,
  // qt fastest within wg -> same-(h,b) blocks co-located.
  const int lid = blockIdx.x;
  const int wg = (lid & 7) * 384 + (lid >> 3);
  const int qt = wg & 3;
  const int hb = wg >> 2;
  const int h = hb % H_;
  const int b = hb / H_;
  const size_t bh = ((size_t)b * H_ + h) * N_ * HD_;
  const bf16* qb = q + bh;
  const bf16* kb = k + bh;
  const bf16* vg = vT_g + ((size_t)b * H_ + h) * HD_ * VTP_;

  // zero this wave's P pad cols [208,224)  (QK pass writes cols 0..207)
  if (quad < 2)
    *(uint4*)(&s_lds[(w * 16 + l15) * SW + 208 + quad * 8]) = (uint4){0, 0, 0, 0};

  // ---- fused pass: S = Q K^T + rpb, P = exp(S), rowsum ----
  const int row0 = qt * 64 + w * 16;
  int qm = row0 + l15; if (qm > N_ - 1) qm = N_ - 1;
  bf16x8 aq0 = *(const bf16x8*)(qb + qm * HD_ + quad * 8);
  bf16x8 aq1 = *(const bf16x8*)(qb + qm * HD_ + 32 + quad * 8);

  int rbase = row0 + quad * 4; if (rbase > N_ - 1) rbase = N_ - 1;

  // 2-deep K pipeline: slot jt&1 computes, slot (jt+1)&1 prefetches
  bf16x8 pk0[2], pk1[2];
  {
    const bf16* kp0 = kb + l15 * HD_ + quad * 8;   // jt=0: kn = l15 (<197, no clamp)
    pk0[0] = *(const bf16x8*)(kp0);
    pk1[0] = *(const bf16x8*)(kp0 + 32);
  }

  float sum[4] = {0.f, 0.f, 0.f, 0.f};
#pragma unroll
  for (int jt = 0; jt < 13; ++jt) {
    const int cur = jt & 1, nxt = cur ^ 1;
    if (jt + 1 < 13) {
      int kn1 = (jt + 1) * 16 + l15; if (kn1 > N_ - 1) kn1 = N_ - 1;
      const bf16* kp = kb + kn1 * HD_ + quad * 8;
      pk0[nxt] = *(const bf16x8*)(kp);
      pk1[nxt] = *(const bf16x8*)(kp + 32);
    }
    int col = jt * 16 + l15;
    int kn = col; if (kn > N_ - 1) kn = N_ - 1;
    // rpbT [h][q-row][k-col]: 4 coalesced scalar loads (lane -> kn contiguous)
    float rbv[4];
#pragma unroll
    for (int r2 = 0; r2 < 4; ++r2) {
      int rn = rbase + r2; if (rn > N_ - 1) rn = N_ - 1;   // clamped lanes are masked below
      rbv[r2] = (float)rpbT[((size_t)h * N_ + rn) * VTP_ + kn];
    }
    f32x4 s = {0.f, 0.f, 0.f, 0.f};
    s = __builtin_amdgcn_mfma_f32_16x16x32_bf16(aq0, pk0[cur], s, 0, 0, 0);
    s = __builtin_amdgcn_mfma_f32_16x16x32_bf16(aq1, pk1[cur], s, 0, 0, 0);
#pragma unroll
    for (int r = 0; r < 4; ++r) {
      int row = row0 + quad * 4 + r;
      // scores are O(10); pads get -30000 -> exp underflows to exactly 0
      float sv = (col < N_ && row < N_) ? (s[r] + rbv[r]) : NEGI_;
      float p = __expf(sv);
      bf16 pb = (bf16)p;
      s_lds[(w * 16 + quad * 4 + r) * SW + col] = pb;
      sum[r] += (float)pb;
    }
  }

  // prefetch phase-B kk=0 V fragments into the shuffle-latency shadow
  bf16x8 bv0[4];
#pragma unroll
  for (int j2 = 0; j2 < 4; ++j2)
    bv0[j2] = *(const bf16x8*)(vg + (j2 * 16 + l15) * VTP_ + quad * 8);

#pragma unroll
  for (int r = 0; r < 4; ++r) {
    sum[r] += __shfl_xor(sum[r], 1);
    sum[r] += __shfl_xor(sum[r], 2);
    sum[r] += __shfl_xor(sum[r], 4);
    sum[r] += __shfl_xor(sum[r], 8);
  }
  float inv[4];
#pragma unroll
  for (int r = 0; r < 4; ++r) inv[r] = 1.0f / fmaxf(sum[r], 1e-20f);

  // ---- phase B: O = P @ V  (V^T fragments straight from global; pads hit exact-zero P) ----
  f32x4 o[4] = {};
  {
    bf16x8 ap = *(const bf16x8*)(&s_lds[(w * 16 + l15) * SW + quad * 8]);
#pragma unroll
    for (int j2 = 0; j2 < 4; ++j2)
      o[j2] = __builtin_amdgcn_mfma_f32_16x16x32_bf16(ap, bv0[j2], o[j2], 0, 0, 0);
  }
#pragma unroll
  for (int kk = 1; kk < 7; ++kk) {
    bf16x8 ap = *(const bf16x8*)(&s_lds[(w * 16 + l15) * SW + kk * 32 + quad * 8]);
#pragma unroll
    for (int j2 = 0; j2 < 4; ++j2) {
      bf16x8 bv = *(const bf16x8*)(vg + (j2 * 16 + l15) * VTP_ + kk * 32 + quad * 8);
      o[j2] = __builtin_amdgcn_mfma_f32_16x16x32_bf16(ap, bv, o[j2], 0, 0, 0);
    }
  }
#pragma unroll
  for (int j2 = 0; j2 < 4; ++j2) {
#pragma unroll
    for (int r = 0; r < 4; ++r) {
      int row = qt * 64 + w * 16 + quad * 4 + r;
      int hd = j2 * 16 + l15;
      if (row < N_)
        out[((size_t)b * N_ + row) * C_ + h * HD_ + hd] = (bf16)(o[j2][r] * inv[r]);
    }
  }
}

// ---------------- launch ----------------
extern "C" void kernel_launch(void* const* d_in, const int* in_sizes, int n_in,
                              void* d_out, int out_size, void* d_ws, size_t ws_size,
                              hipStream_t stream)
{
  const float* x      = (const float*)d_in[0];
  const float* qkv_w  = (const float*)d_in[1];
  const float* q_bias = (const float*)d_in[2];
  const float* v_bias = (const float*)d_in[3];
  const float* q_la   = (const float*)d_in[4];
  const float* q_lb   = (const float*)d_in[5];
  const float* k_la   = (const float*)d_in[6];
  const float* k_lb   = (const float*)d_in[7];
  const float* v_la   = (const float*)d_in[8];
  const float* v_lb   = (const float*)d_in[9];
  const float* rpt    = (const float*)d_in[10];
  const float* proj_w = (const float*)d_in[11];
  const float* proj_b = (const float*)d_in[12];
  const int*   rpi    = (const int*)d_in[13];
  float* out = (float*)d_out;

  char* ws = (char*)d_ws;
  // layout (16B-aligned); xbf dead after gemm<0>, reused as aout
  bf16*  xbf   = (bf16*)(ws);                         // 19,365,888 B
  bf16*  aout  = (bf16*)(ws);                         // alias
  bf16*  weff  = (bf16*)(ws + 19365888);              //  3,538,944 B
  float* biasf = (float*)(ws + 22904832);             //      9,216 B
  bf16*  pwbf  = (bf16*)(ws + 22914048);              //  1,179,648 B
  bf16*  qbuf  = (bf16*)(ws + 24093696);              // 19,365,888 B
  bf16*  kbuf  = (bf16*)(ws + 43459584);              // 19,365,888 B
  bf16*  vbufT = (bf16*)(ws + 62825472);              // 19,660,800 (+128 slack)
  bf16*  rpbT  = (bf16*)(ws + 82486400);              // 945,600
  // total ws use ≈ 83.4 MB

  prep_kernel<<<13748, 256, 0, stream>>>(
      x, proj_w, qkv_w, q_bias, v_bias, q_la, q_lb, k_la, k_lb, v_la, v_lb,
      rpt, rpi, xbf, pwbf, weff, biasf, rpbT);

  gemm_bt<0, 128><<<dim3(18, 99), 512, 0, stream>>>(
      xbf, weff, biasf, nullptr, M_, 3 * C_, C_, qbuf, kbuf, vbufT);

  // flat 3072-block grid; XCD-chunked swizzle inside the kernel
  attn_kernel<<<dim3(3072), 256, 0, stream>>>(qbuf, kbuf, vbufT, rpbT, aout);

  gemm_bt<1, 128><<<dim3(6, 99), 512, 0, stream>>>(
      aout, pwbf, proj_b, out, M_, C_, C_, nullptr, nullptr, nullptr);
}

// Round 9
// 271.680 us; speedup vs baseline: 1.7166x; 1.0351x over previous
//
#include <hip/hip_runtime.h>

typedef __bf16 bf16;
typedef __attribute__((ext_vector_type(8))) __bf16 bf16x8;
typedef __attribute__((ext_vector_type(4))) __bf16 bf16x4;
typedef __attribute__((ext_vector_type(4))) float f32x4;

#define B_    64
#define N_    197
#define C_    768
#define H_    12
#define HD_   64
#define SCALE_ 0.125f
#define NM_   (N_*N_)         // 38809
#define M_    (B_*N_)         // 12608
#define NEGI_ (-30000.0f)
#define VTP_  200             // vbufT / rpbT row pad

#define GLL16(gptr, lptr) \
  __builtin_amdgcn_global_load_lds((const __attribute__((address_space(1))) unsigned int*)(gptr), \
                                   (__attribute__((address_space(3))) unsigned int*)(lptr), 16, 0, 0)

// ---------------- fused prep: cast x/proj_w, W_eff + bias, rpbT ----------------
// blocks [0,5016): cast; [5016,11928): weff; [11928,13748): rpbT
// rpbT layout [h][q-row n][k-col m] (+VTP_ pad): unit-stride prep write,
// coalesced attn read (R6 win).
__global__ __launch_bounds__(256) void prep_kernel(
    const float* __restrict__ x, const float* __restrict__ pw,
    const float* __restrict__ qkv_w, const float* __restrict__ q_bias, const float* __restrict__ v_bias,
    const float* __restrict__ qa, const float* __restrict__ qb,
    const float* __restrict__ ka, const float* __restrict__ kb,
    const float* __restrict__ va, const float* __restrict__ vb,
    const float* __restrict__ table, const int* __restrict__ rpi,
    bf16* __restrict__ xbf, bf16* __restrict__ pwbf,
    bf16* __restrict__ weff, float* __restrict__ biasf, bf16* __restrict__ rpbT)
{
  const int bid = blockIdx.x, tid = threadIdx.x;
  if (bid < 5016) {
    const size_t n1 = (size_t)M_ * C_;   // 9,682,944
    size_t i8 = ((size_t)bid * 256 + tid) * 8;
    const float* src; bf16* dst; size_t off;
    if (i8 < n1) { src = x;  dst = xbf;  off = i8; }
    else         { src = pw; dst = pwbf; off = i8 - n1; }
    float4 f0 = *(const float4*)(src + off);
    float4 f1 = *(const float4*)(src + off + 4);
    bf16x8 v8;
    v8[0] = (bf16)f0.x; v8[1] = (bf16)f0.y; v8[2] = (bf16)f0.z; v8[3] = (bf16)f0.w;
    v8[4] = (bf16)f1.x; v8[5] = (bf16)f1.y; v8[6] = (bf16)f1.z; v8[7] = (bf16)f1.w;
    *(bf16x8*)(dst + off) = v8;
  } else if (bid < 11928) {
    int idx = (bid - 5016) * 256 + tid;          // < 1,769,472 exact
    int d = idx / C_, c = idx - d * C_;
    int sel = d / C_, dd = d - sel * C_;
    const float* a  = (sel == 0) ? qa : (sel == 1) ? ka : va;
    const float* bw = (sel == 0) ? qb : (sel == 1) ? kb : vb;
    float acc = qkv_w[idx];
#pragma unroll
    for (int r = 0; r < 24; ++r)
      acc += bw[dd * 24 + r] * a[r * C_ + c];
    weff[idx] = (bf16)acc;
    if (c == 0)
      biasf[d] = (sel == 0) ? q_bias[dd] : (sel == 2) ? v_bias[dd] : 0.0f;
  } else {
    int idx = (bid - 11928) * 256 + tid;
    if (idx < H_ * NM_) {
      int h = idx / NM_, nm = idx - h * NM_;
      int n = nm / N_, m = nm - n * N_;
      rpbT[((size_t)h * N_ + n) * VTP_ + m] = (bf16)table[rpi[nm] * H_ + h];  // unit-stride write
    }
  }
}

// ---------------- gemm_bt: C[M,Nn] = A[M,K] @ B[Nn,K]^T, bf16 operands ----------------
// R7 winner structure (BM=128, 8 waves, 32KB LDS, 32 waves/CU, packed bf16x4 v-stores)
// + R9: m204 bijective XCD-chunked block swizzle. Round-robin dispatch spread the 18
// row-mates (shared 196KB A-panel) and column-mates (shared B-panels) across XCDs ->
// 23MB working set per 4MB L2 -> FETCH 97MB vs 23MB unique. Chunking gives each XCD
// ~12 contiguous rows: concurrent set ~1.4MB A + 3.5MB B ~ L2-resident.
// MODE 0: scatter q(xSCALE)/k -> [B,H,N,HD]; v -> TRANSPOSED [B,H,HD,VTP_]
// MODE 1: C[m,d] = acc + biasp[d] -> f32 out
template<int MODE, int BM>
__global__ __launch_bounds__(512, 8) void gemm_bt(
    const bf16* __restrict__ A, const bf16* __restrict__ Bw,
    const float* __restrict__ biasp,
    float* __restrict__ Coutf, int M, int Nn, int K,
    bf16* __restrict__ qo, bf16* __restrict__ ko, bf16* __restrict__ vo)
{
  __shared__ __align__(16) bf16 As[BM * 64];
  __shared__ __align__(16) bf16 Bs[128 * 64];
  const int tid = threadIdx.x;
  const int lane = tid & 63, w = tid >> 6;          // 8 waves
  const int l15 = lane & 15, quad = lane >> 4;
  const int wm = (w & 1) * 64;                      // M half (64 rows)
  const int wn = (w >> 1) * 32;                     // N quarter (32 cols)
  constexpr int NF = 2;                             // B-fragments per wave

  // m204 bijective XCD-chunked swizzle: orig%8 = XCD (round-robin dispatch);
  // remap so XCD k processes a contiguous x-fastest chunk of the grid.
  const int ntx = gridDim.x;
  const int nwg = ntx * gridDim.y;
  const int orig = blockIdx.y * ntx + blockIdx.x;
  const int xcd = orig & 7, hi = orig >> 3;
  const int qq = nwg >> 3, rr = nwg & 7;
  const int wg = (xcd < rr ? xcd * (qq + 1) : rr * (qq + 1) + (xcd - rr) * qq) + hi;
  const int rowB0 = (wg % ntx) * 128;   // N-tile (fastest-varying)
  const int rowA0 = (wg / ntx) * BM;    // M-tile

  f32x4 acc[4][NF] = {};

  for (int kt = 0; kt < K; kt += 64) {
#pragma unroll
    for (int i = 0; i < BM / 64; ++i) {            // A: BM x 64 tile
      int lin = i * 512 + tid;
      int r  = lin >> 3;                           // 0..BM-1
      int cb = lin & 7;                            // LDS column block
      int csw = ((cb ^ (r & 7)) << 3);             // swizzled global column (elems)
      int ga = rowA0 + r; if (ga > M - 1) ga = M - 1;
      GLL16(A + (size_t)ga * K + kt + csw, &As[lin * 8]);
    }
#pragma unroll
    for (int i = 0; i < 2; ++i) {                  // B: 128 x 64 tile
      int lin = i * 512 + tid;
      int r  = lin >> 3;
      int cb = lin & 7;
      int csw = ((cb ^ (r & 7)) << 3);
      int gb = rowB0 + r; if (gb > Nn - 1) gb = Nn - 1;
      GLL16(Bw + (size_t)gb * K + kt + csw, &Bs[lin * 8]);
    }
    __syncthreads();
#pragma unroll
    for (int ks = 0; ks < 2; ++ks) {
      const int cb = ks * 4 + quad;                // k-block 0..7
      const int sw = (cb ^ (l15 & 7)) << 3;
      bf16x8 af[4], bfr[NF];
#pragma unroll
      for (int i = 0; i < 4; ++i)
        af[i] = *(const bf16x8*)(&As[(wm + i * 16 + l15) * 64 + sw]);
#pragma unroll
      for (int j = 0; j < NF; ++j)
        bfr[j] = *(const bf16x8*)(&Bs[(wn + j * 16 + l15) * 64 + sw]);
#pragma unroll
      for (int i = 0; i < 4; ++i)
#pragma unroll
        for (int j = 0; j < NF; ++j)
          acc[i][j] = __builtin_amdgcn_mfma_f32_16x16x32_bf16(af[i], bfr[j], acc[i][j], 0, 0, 0);
    }
    __syncthreads();
  }

#pragma unroll
  for (int i = 0; i < 4; ++i) {
#pragma unroll
    for (int j = 0; j < NF; ++j) {
      const int m0 = rowA0 + wm + i * 16 + quad * 4;
      const int d  = rowB0 + wn + j * 16 + l15;
      const float bias = biasp[d];
      if (MODE == 0) {
        const int sel = d / C_, dd = d - sel * C_;
        const int h = dd >> 6, hd = dd & 63;
        if (sel == 2) {
          // v transposed: lane's 4 r-values = consecutive n for fixed (b,h,hd) row
          int b0 = m0 / N_, n0 = m0 - b0 * N_;
          if (m0 + 3 < M && n0 + 3 < N_) {
            bf16x4 pv;
#pragma unroll
            for (int r = 0; r < 4; ++r) pv[r] = (bf16)(acc[i][j][r] + bias);
            *(bf16x4*)(vo + (((size_t)b0 * H_ + h) * HD_ + hd) * VTP_ + n0) = pv;
          } else {
#pragma unroll
            for (int r = 0; r < 4; ++r) {
              int m = m0 + r; if (m >= M) continue;
              int b = m / N_, n = m - b * N_;
              vo[(((size_t)b * H_ + h) * HD_ + hd) * VTP_ + n] = (bf16)(acc[i][j][r] + bias);
            }
          }
        } else {
#pragma unroll
          for (int r = 0; r < 4; ++r) {
            int m = m0 + r; if (m >= M) continue;
            int b = m / N_, n = m - b * N_;
            float v = acc[i][j][r] + bias;
            if (sel == 0)
              qo[(((size_t)b * H_ + h) * N_ + n) * HD_ + hd] = (bf16)(v * SCALE_);
            else
              ko[(((size_t)b * H_ + h) * N_ + n) * HD_ + hd] = (bf16)v;
          }
        }
      } else {
#pragma unroll
        for (int r = 0; r < 4; ++r) {
          int m = m0 + r; if (m >= M) continue;
          Coutf[(size_t)m * Nn + d] = acc[i][j][r] + bias;
        }
      }
    }
  }
}

// ---------------- attention: barrier-free, max-free softmax ----------------
// R8: XCD-chunked swizzle + 2-deep K prefetch. R9: 2-deep V prefetch in the PV
// loop (kk=0,1 preloaded in the shuffle-latency shadow; prefetch kk+2 after each
// MFMA quad; fully unrolled -> static indices) + s_setprio around MFMA clusters
// (m191: positive for attn's independent-wave structure). VGPR ~60 -> ~92, still
// 5 waves/SIMD (20 waves/CU LDS cap unchanged).
#define SW 232   // P row stride (bf16 elems); PV consumes cols 0..223
__global__ __launch_bounds__(256) void attn_kernel(
    const bf16* __restrict__ q, const bf16* __restrict__ k, const bf16* __restrict__ vT_g,
    const bf16* __restrict__ rpbT, bf16* __restrict__ out)
{
  __shared__ __align__(16) bf16 s_lds[64 * SW];   // P tile (each wave owns its 16 rows)

  const int tid = threadIdx.x;
  const int lane = tid & 63, w = tid >> 6;
  const int l15 = lane & 15, quad = lane >> 4;
  // XCD-chunked bijection (3072 = 8 XCDs x 384): contiguous wg-chunk per XCD,
  // qt fastest within wg -> same-(h,b) blocks co-located.
  const int lid = blockIdx.x;
  const int wg = (lid & 7) * 384 + (lid >> 3);
  const int qt = wg & 3;
  const int hb = wg >> 2;
  const int h = hb % H_;
  const int b = hb / H_;
  const size_t bh = ((size_t)b * H_ + h) * N_ * HD_;
  const bf16* qb = q + bh;
  const bf16* kb = k + bh;
  const bf16* vg = vT_g + ((size_t)b * H_ + h) * HD_ * VTP_;

  // zero this wave's P pad cols [208,224)  (QK pass writes cols 0..207)
  if (quad < 2)
    *(uint4*)(&s_lds[(w * 16 + l15) * SW + 208 + quad * 8]) = (uint4){0, 0, 0, 0};

  // ---- fused pass: S = Q K^T + rpb, P = exp(S), rowsum ----
  const int row0 = qt * 64 + w * 16;
  int qm = row0 + l15; if (qm > N_ - 1) qm = N_ - 1;
  bf16x8 aq0 = *(const bf16x8*)(qb + qm * HD_ + quad * 8);
  bf16x8 aq1 = *(const bf16x8*)(qb + qm * HD_ + 32 + quad * 8);

  int rbase = row0 + quad * 4; if (rbase > N_ - 1) rbase = N_ - 1;

  // 2-deep K pipeline: slot jt&1 computes, slot (jt+1)&1 prefetches
  bf16x8 pk0[2], pk1[2];
  {
    const bf16* kp0 = kb + l15 * HD_ + quad * 8;   // jt=0: kn = l15 (<197, no clamp)
    pk0[0] = *(const bf16x8*)(kp0);
    pk1[0] = *(const bf16x8*)(kp0 + 32);
  }

  float sum[4] = {0.f, 0.f, 0.f, 0.f};
#pragma unroll
  for (int jt = 0; jt < 13; ++jt) {
    const int cur = jt & 1, nxt = cur ^ 1;
    if (jt + 1 < 13) {
      int kn1 = (jt + 1) * 16 + l15; if (kn1 > N_ - 1) kn1 = N_ - 1;
      const bf16* kp = kb + kn1 * HD_ + quad * 8;
      pk0[nxt] = *(const bf16x8*)(kp);
      pk1[nxt] = *(const bf16x8*)(kp + 32);
    }
    int col = jt * 16 + l15;
    int kn = col; if (kn > N_ - 1) kn = N_ - 1;
    // rpbT [h][q-row][k-col]: 4 coalesced scalar loads (lane -> kn contiguous)
    float rbv[4];
#pragma unroll
    for (int r2 = 0; r2 < 4; ++r2) {
      int rn = rbase + r2; if (rn > N_ - 1) rn = N_ - 1;   // clamped lanes are masked below
      rbv[r2] = (float)rpbT[((size_t)h * N_ + rn) * VTP_ + kn];
    }
    f32x4 s = {0.f, 0.f, 0.f, 0.f};
    __builtin_amdgcn_s_setprio(1);
    s = __builtin_amdgcn_mfma_f32_16x16x32_bf16(aq0, pk0[cur], s, 0, 0, 0);
    s = __builtin_amdgcn_mfma_f32_16x16x32_bf16(aq1, pk1[cur], s, 0, 0, 0);
    __builtin_amdgcn_s_setprio(0);
#pragma unroll
    for (int r = 0; r < 4; ++r) {
      int row = row0 + quad * 4 + r;
      // scores are O(10); pads get -30000 -> exp underflows to exactly 0
      float sv = (col < N_ && row < N_) ? (s[r] + rbv[r]) : NEGI_;
      float p = __expf(sv);
      bf16 pb = (bf16)p;
      s_lds[(w * 16 + quad * 4 + r) * SW + col] = pb;
      sum[r] += (float)pb;
    }
  }

  // preload PV kk=0 and kk=1 V fragments into the shuffle-latency shadow
  bf16x8 vbuf[2][4];
#pragma unroll
  for (int j2 = 0; j2 < 4; ++j2) {
    vbuf[0][j2] = *(const bf16x8*)(vg + (j2 * 16 + l15) * VTP_ + quad * 8);
    vbuf[1][j2] = *(const bf16x8*)(vg + (j2 * 16 + l15) * VTP_ + 32 + quad * 8);
  }

#pragma unroll
  for (int r = 0; r < 4; ++r) {
    sum[r] += __shfl_xor(sum[r], 1);
    sum[r] += __shfl_xor(sum[r], 2);
    sum[r] += __shfl_xor(sum[r], 4);
    sum[r] += __shfl_xor(sum[r], 8);
  }
  float inv[4];
#pragma unroll
  for (int r = 0; r < 4; ++r) inv[r] = 1.0f / fmaxf(sum[r], 1e-20f);

  // ---- phase B: O = P @ V  (2-deep V prefetch; pads hit exact-zero P) ----
  f32x4 o[4] = {};
#pragma unroll
  for (int kk = 0; kk < 7; ++kk) {
    const int cur = kk & 1;
    bf16x8 ap = *(const bf16x8*)(&s_lds[(w * 16 + l15) * SW + kk * 32 + quad * 8]);
    __builtin_amdgcn_s_setprio(1);
#pragma unroll
    for (int j2 = 0; j2 < 4; ++j2)
      o[j2] = __builtin_amdgcn_mfma_f32_16x16x32_bf16(ap, vbuf[cur][j2], o[j2], 0, 0, 0);
    __builtin_amdgcn_s_setprio(0);
    if (kk + 2 < 7) {
#pragma unroll
      for (int j2 = 0; j2 < 4; ++j2)
        vbuf[cur][j2] = *(const bf16x8*)(vg + (j2 * 16 + l15) * VTP_ + (kk + 2) * 32 + quad * 8);
    }
  }
#pragma unroll
  for (int j2 = 0; j2 < 4; ++j2) {
#pragma unroll
    for (int r = 0; r < 4; ++r) {
      int row = qt * 64 + w * 16 + quad * 4 + r;
      int hd = j2 * 16 + l15;
      if (row < N_)
        out[((size_t)b * N_ + row) * C_ + h * HD_ + hd] = (bf16)(o[j2][r] * inv[r]);
    }
  }
}

// ---------------- launch ----------------
extern "C" void kernel_launch(void* const* d_in, const int* in_sizes, int n_in,
                              void* d_out, int out_size, void* d_ws, size_t ws_size,
                              hipStream_t stream)
{
  const float* x      = (const float*)d_in[0];
  const float* qkv_w  = (const float*)d_in[1];
  const float* q_bias = (const float*)d_in[2];
  const float* v_bias = (const float*)d_in[3];
  const float* q_la   = (const float*)d_in[4];
  const float* q_lb   = (const float*)d_in[5];
  const float* k_la   = (const float*)d_in[6];
  const float* k_lb   = (const float*)d_in[7];
  const float* v_la   = (const float*)d_in[8];
  const float* v_lb   = (const float*)d_in[9];
  const float* rpt    = (const float*)d_in[10];
  const float* proj_w = (const float*)d_in[11];
  const float* proj_b = (const float*)d_in[12];
  const int*   rpi    = (const int*)d_in[13];
  float* out = (float*)d_out;

  char* ws = (char*)d_ws;
  // layout (16B-aligned); xbf dead after gemm<0>, reused as aout
  bf16*  xbf   = (bf16*)(ws);                         // 19,365,888 B
  bf16*  aout  = (bf16*)(ws);                         // alias
  bf16*  weff  = (bf16*)(ws + 19365888);              //  3,538,944 B
  float* biasf = (float*)(ws + 22904832);             //      9,216 B
  bf16*  pwbf  = (bf16*)(ws + 22914048);              //  1,179,648 B
  bf16*  qbuf  = (bf16*)(ws + 24093696);              // 19,365,888 B
  bf16*  kbuf  = (bf16*)(ws + 43459584);              // 19,365,888 B
  bf16*  vbufT = (bf16*)(ws + 62825472);              // 19,660,800 (+128 slack)
  bf16*  rpbT  = (bf16*)(ws + 82486400);              // 945,600
  // total ws use ≈ 83.4 MB

  prep_kernel<<<13748, 256, 0, stream>>>(
      x, proj_w, qkv_w, q_bias, v_bias, q_la, q_lb, k_la, k_lb, v_la, v_lb,
      rpt, rpi, xbf, pwbf, weff, biasf, rpbT);

  gemm_bt<0, 128><<<dim3(18, 99), 512, 0, stream>>>(
      xbf, weff, biasf, nullptr, M_, 3 * C_, C_, qbuf, kbuf, vbufT);

  // flat 3072-block grid; XCD-chunked swizzle inside the kernel
  attn_kernel<<<dim3(3072), 256, 0, stream>>>(qbuf, kbuf, vbufT, rpbT, aout);

  gemm_bt<1, 128><<<dim3(6, 99), 512, 0, stream>>>(
      aout, pwbf, proj_b, out, M_, C_, C_, nullptr, nullptr, nullptr);
}

// Round 10
// 270.197 us; speedup vs baseline: 1.7260x; 1.0055x over previous
//
#include <hip/hip_runtime.h>

typedef __bf16 bf16;
typedef __attribute__((ext_vector_type(8))) __bf16 bf16x8;
typedef __attribute__((ext_vector_type(4))) __bf16 bf16x4;
typedef __attribute__((ext_vector_type(4))) float f32x4;

#define B_    64
#define N_    197
#define C_    768
#define H_    12
#define HD_   64
#define SCALE_ 0.125f
#define NM_   (N_*N_)         // 38809
#define M_    (B_*N_)         // 12608
#define NEGI_ (-30000.0f)
#define VTP_  200             // vbufT / rpbT row pad

#define GLL16(gptr, lptr) \
  __builtin_amdgcn_global_load_lds((const __attribute__((address_space(1))) unsigned int*)(gptr), \
                                   (__attribute__((address_space(3))) unsigned int*)(lptr), 16, 0, 0)

// ---------------- fused prep: cast x/proj_w, W_eff + bias, rpbT ----------------
// blocks [0,5016): cast; [5016,11928): weff; [11928,13748): rpbT
// rpbT layout [h][q-row n][k-col m] (+VTP_ pad): unit-stride prep write,
// coalesced attn read (R6 win).
__global__ __launch_bounds__(256) void prep_kernel(
    const float* __restrict__ x, const float* __restrict__ pw,
    const float* __restrict__ qkv_w, const float* __restrict__ q_bias, const float* __restrict__ v_bias,
    const float* __restrict__ qa, const float* __restrict__ qb,
    const float* __restrict__ ka, const float* __restrict__ kb,
    const float* __restrict__ va, const float* __restrict__ vb,
    const float* __restrict__ table, const int* __restrict__ rpi,
    bf16* __restrict__ xbf, bf16* __restrict__ pwbf,
    bf16* __restrict__ weff, float* __restrict__ biasf, bf16* __restrict__ rpbT)
{
  const int bid = blockIdx.x, tid = threadIdx.x;
  if (bid < 5016) {
    const size_t n1 = (size_t)M_ * C_;   // 9,682,944
    size_t i8 = ((size_t)bid * 256 + tid) * 8;
    const float* src; bf16* dst; size_t off;
    if (i8 < n1) { src = x;  dst = xbf;  off = i8; }
    else         { src = pw; dst = pwbf; off = i8 - n1; }
    float4 f0 = *(const float4*)(src + off);
    float4 f1 = *(const float4*)(src + off + 4);
    bf16x8 v8;
    v8[0] = (bf16)f0.x; v8[1] = (bf16)f0.y; v8[2] = (bf16)f0.z; v8[3] = (bf16)f0.w;
    v8[4] = (bf16)f1.x; v8[5] = (bf16)f1.y; v8[6] = (bf16)f1.z; v8[7] = (bf16)f1.w;
    *(bf16x8*)(dst + off) = v8;
  } else if (bid < 11928) {
    int idx = (bid - 5016) * 256 + tid;          // < 1,769,472 exact
    int d = idx / C_, c = idx - d * C_;
    int sel = d / C_, dd = d - sel * C_;
    const float* a  = (sel == 0) ? qa : (sel == 1) ? ka : va;
    const float* bw = (sel == 0) ? qb : (sel == 1) ? kb : vb;
    float acc = qkv_w[idx];
#pragma unroll
    for (int r = 0; r < 24; ++r)
      acc += bw[dd * 24 + r] * a[r * C_ + c];
    weff[idx] = (bf16)acc;
    if (c == 0)
      biasf[d] = (sel == 0) ? q_bias[dd] : (sel == 2) ? v_bias[dd] : 0.0f;
  } else {
    int idx = (bid - 11928) * 256 + tid;
    if (idx < H_ * NM_) {
      int h = idx / NM_, nm = idx - h * NM_;
      int n = nm / N_, m = nm - n * N_;
      rpbT[((size_t)h * N_ + n) * VTP_ + m] = (bf16)table[rpi[nm] * H_ + h];  // unit-stride write
    }
  }
}

// ---------------- gemm_bt: C[M,Nn] = A[M,K] @ B[Nn,K]^T, bf16 operands ----------------
// R9 winner, UNTOUCHED: BM=128, 8 waves, 32KB LDS, 32 waves/CU, packed bf16x4 v-stores,
// m204 bijective XCD-chunked swizzle (dropped gemm<0> FETCH + out of top-5).
// MODE 0: scatter q(xSCALE)/k -> [B,H,N,HD]; v -> TRANSPOSED [B,H,HD,VTP_]
// MODE 1: C[m,d] = acc + biasp[d] -> f32 out
template<int MODE, int BM>
__global__ __launch_bounds__(512, 8) void gemm_bt(
    const bf16* __restrict__ A, const bf16* __restrict__ Bw,
    const float* __restrict__ biasp,
    float* __restrict__ Coutf, int M, int Nn, int K,
    bf16* __restrict__ qo, bf16* __restrict__ ko, bf16* __restrict__ vo)
{
  __shared__ __align__(16) bf16 As[BM * 64];
  __shared__ __align__(16) bf16 Bs[128 * 64];
  const int tid = threadIdx.x;
  const int lane = tid & 63, w = tid >> 6;          // 8 waves
  const int l15 = lane & 15, quad = lane >> 4;
  const int wm = (w & 1) * 64;                      // M half (64 rows)
  const int wn = (w >> 1) * 32;                     // N quarter (32 cols)
  constexpr int NF = 2;                             // B-fragments per wave

  // m204 bijective XCD-chunked swizzle: orig%8 = XCD (round-robin dispatch);
  // remap so XCD k processes a contiguous x-fastest chunk of the grid.
  const int ntx = gridDim.x;
  const int nwg = ntx * gridDim.y;
  const int orig = blockIdx.y * ntx + blockIdx.x;
  const int xcd = orig & 7, hi = orig >> 3;
  const int qq = nwg >> 3, rr = nwg & 7;
  const int wg = (xcd < rr ? xcd * (qq + 1) : rr * (qq + 1) + (xcd - rr) * qq) + hi;
  const int rowB0 = (wg % ntx) * 128;   // N-tile (fastest-varying)
  const int rowA0 = (wg / ntx) * BM;    // M-tile

  f32x4 acc[4][NF] = {};

  for (int kt = 0; kt < K; kt += 64) {
#pragma unroll
    for (int i = 0; i < BM / 64; ++i) {            // A: BM x 64 tile
      int lin = i * 512 + tid;
      int r  = lin >> 3;                           // 0..BM-1
      int cb = lin & 7;                            // LDS column block
      int csw = ((cb ^ (r & 7)) << 3);             // swizzled global column (elems)
      int ga = rowA0 + r; if (ga > M - 1) ga = M - 1;
      GLL16(A + (size_t)ga * K + kt + csw, &As[lin * 8]);
    }
#pragma unroll
    for (int i = 0; i < 2; ++i) {                  // B: 128 x 64 tile
      int lin = i * 512 + tid;
      int r  = lin >> 3;
      int cb = lin & 7;
      int csw = ((cb ^ (r & 7)) << 3);
      int gb = rowB0 + r; if (gb > Nn - 1) gb = Nn - 1;
      GLL16(Bw + (size_t)gb * K + kt + csw, &Bs[lin * 8]);
    }
    __syncthreads();
#pragma unroll
    for (int ks = 0; ks < 2; ++ks) {
      const int cb = ks * 4 + quad;                // k-block 0..7
      const int sw = (cb ^ (l15 & 7)) << 3;
      bf16x8 af[4], bfr[NF];
#pragma unroll
      for (int i = 0; i < 4; ++i)
        af[i] = *(const bf16x8*)(&As[(wm + i * 16 + l15) * 64 + sw]);
#pragma unroll
      for (int j = 0; j < NF; ++j)
        bfr[j] = *(const bf16x8*)(&Bs[(wn + j * 16 + l15) * 64 + sw]);
#pragma unroll
      for (int i = 0; i < 4; ++i)
#pragma unroll
        for (int j = 0; j < NF; ++j)
          acc[i][j] = __builtin_amdgcn_mfma_f32_16x16x32_bf16(af[i], bfr[j], acc[i][j], 0, 0, 0);
    }
    __syncthreads();
  }

#pragma unroll
  for (int i = 0; i < 4; ++i) {
#pragma unroll
    for (int j = 0; j < NF; ++j) {
      const int m0 = rowA0 + wm + i * 16 + quad * 4;
      const int d  = rowB0 + wn + j * 16 + l15;
      const float bias = biasp[d];
      if (MODE == 0) {
        const int sel = d / C_, dd = d - sel * C_;
        const int h = dd >> 6, hd = dd & 63;
        if (sel == 2) {
          // v transposed: lane's 4 r-values = consecutive n for fixed (b,h,hd) row
          int b0 = m0 / N_, n0 = m0 - b0 * N_;
          if (m0 + 3 < M && n0 + 3 < N_) {
            bf16x4 pv;
#pragma unroll
            for (int r = 0; r < 4; ++r) pv[r] = (bf16)(acc[i][j][r] + bias);
            *(bf16x4*)(vo + (((size_t)b0 * H_ + h) * HD_ + hd) * VTP_ + n0) = pv;
          } else {
#pragma unroll
            for (int r = 0; r < 4; ++r) {
              int m = m0 + r; if (m >= M) continue;
              int b = m / N_, n = m - b * N_;
              vo[(((size_t)b * H_ + h) * HD_ + hd) * VTP_ + n] = (bf16)(acc[i][j][r] + bias);
            }
          }
        } else {
#pragma unroll
          for (int r = 0; r < 4; ++r) {
            int m = m0 + r; if (m >= M) continue;
            int b = m / N_, n = m - b * N_;
            float v = acc[i][j][r] + bias;
            if (sel == 0)
              qo[(((size_t)b * H_ + h) * N_ + n) * HD_ + hd] = (bf16)(v * SCALE_);
            else
              ko[(((size_t)b * H_ + h) * N_ + n) * HD_ + hd] = (bf16)v;
          }
        }
      } else {
#pragma unroll
        for (int r = 0; r < 4; ++r) {
          int m = m0 + r; if (m >= M) continue;
          Coutf[(size_t)m * Nn + d] = acc[i][j][r] + bias;
        }
      }
    }
  }
}

// ---------------- attention: barrier-free, max-free softmax, INTERLEAVED QK/PV ----------------
// R10: R9 showed FETCH 86->32MB with time FLAT at 67.7us -> attn is compute/latency
// bound internally, not memory. The serial {13-iter QK+exp} -> {7-iter PV} phase split
// is the critical path. Fix: PV(kk) consumes only P-cols [32kk,32kk+32) = output of
// QK(2kk),QK(2kk+1), and o accumulates UNnormalized (inv applied at store), so PV
// interleaves after each QK pair. Same-wave LDS write->read (lgkmcnt, barrier-free).
// PV MFMAs now overlap the next pair's exp/VALU chain. Bit-identical accumulation order.
// K prefetch 2-deep; V 1-deep (loads fly under the 2 QK iters of the pair).
#define SW 232   // P row stride (bf16 elems); PV consumes cols 0..223
__global__ __launch_bounds__(256) void attn_kernel(
    const bf16* __restrict__ q, const bf16* __restrict__ k, const bf16* __restrict__ vT_g,
    const bf16* __restrict__ rpbT, bf16* __restrict__ out)
{
  __shared__ __align__(16) bf16 s_lds[64 * SW];   // P tile (each wave owns its 16 rows)

  const int tid = threadIdx.x;
  const int lane = tid & 63, w = tid >> 6;
  const int l15 = lane & 15, quad = lane >> 4;
  // XCD-chunked bijection (3072 = 8 XCDs x 384): contiguous wg-chunk per XCD,
  // qt fastest within wg -> same-(h,b) blocks co-located.
  const int lid = blockIdx.x;
  const int wg = (lid & 7) * 384 + (lid >> 3);
  const int qt = wg & 3;
  const int hb = wg >> 2;
  const int h = hb % H_;
  const int b = hb / H_;
  const size_t bh = ((size_t)b * H_ + h) * N_ * HD_;
  const bf16* qb = q + bh;
  const bf16* kb = k + bh;
  const bf16* vg = vT_g + ((size_t)b * H_ + h) * HD_ * VTP_;

  // zero this wave's P pad cols [208,224)  (QK pass writes cols 0..207)
  if (quad < 2)
    *(uint4*)(&s_lds[(w * 16 + l15) * SW + 208 + quad * 8]) = (uint4){0, 0, 0, 0};

  const int row0 = qt * 64 + w * 16;
  int qm = row0 + l15; if (qm > N_ - 1) qm = N_ - 1;
  bf16x8 aq0 = *(const bf16x8*)(qb + qm * HD_ + quad * 8);
  bf16x8 aq1 = *(const bf16x8*)(qb + qm * HD_ + 32 + quad * 8);

  int rbase = row0 + quad * 4; if (rbase > N_ - 1) rbase = N_ - 1;

  // 2-deep K pipeline: slot jt&1 computes, slot (jt+1)&1 prefetches
  bf16x8 pk0[2], pk1[2];
  {
    const bf16* kp0 = kb + l15 * HD_ + quad * 8;   // jt=0: kn = l15 (<197, no clamp)
    pk0[0] = *(const bf16x8*)(kp0);
    pk1[0] = *(const bf16x8*)(kp0 + 32);
  }
  // 1-deep V: fragments for current kk (loads fly under the 2 preceding QK iters)
  bf16x8 vb0[4];
#pragma unroll
  for (int j2 = 0; j2 < 4; ++j2)
    vb0[j2] = *(const bf16x8*)(vg + (j2 * 16 + l15) * VTP_ + quad * 8);

  float sum[4] = {0.f, 0.f, 0.f, 0.f};
  f32x4 o[4] = {};

  auto QK = [&](int jt) {
    const int cur = jt & 1, nxt = cur ^ 1;
    if (jt + 1 < 13) {
      int kn1 = (jt + 1) * 16 + l15; if (kn1 > N_ - 1) kn1 = N_ - 1;
      const bf16* kp = kb + kn1 * HD_ + quad * 8;
      pk0[nxt] = *(const bf16x8*)(kp);
      pk1[nxt] = *(const bf16x8*)(kp + 32);
    }
    int col = jt * 16 + l15;
    int kn = col; if (kn > N_ - 1) kn = N_ - 1;
    // rpbT [h][q-row][k-col]: 4 coalesced scalar loads (lane -> kn contiguous)
    float rbv[4];
#pragma unroll
    for (int r2 = 0; r2 < 4; ++r2) {
      int rn = rbase + r2; if (rn > N_ - 1) rn = N_ - 1;   // clamped lanes are masked below
      rbv[r2] = (float)rpbT[((size_t)h * N_ + rn) * VTP_ + kn];
    }
    f32x4 s = {0.f, 0.f, 0.f, 0.f};
    __builtin_amdgcn_s_setprio(1);
    s = __builtin_amdgcn_mfma_f32_16x16x32_bf16(aq0, pk0[cur], s, 0, 0, 0);
    s = __builtin_amdgcn_mfma_f32_16x16x32_bf16(aq1, pk1[cur], s, 0, 0, 0);
    __builtin_amdgcn_s_setprio(0);
#pragma unroll
    for (int r = 0; r < 4; ++r) {
      int row = row0 + quad * 4 + r;
      // scores are O(10); pads get -30000 -> exp underflows to exactly 0
      float sv = (col < N_ && row < N_) ? (s[r] + rbv[r]) : NEGI_;
      float p = __expf(sv);
      bf16 pb = (bf16)p;
      s_lds[(w * 16 + quad * 4 + r) * SW + col] = pb;
      sum[r] += (float)pb;
    }
  };

  auto PV = [&](int kk) {
    bf16x8 ap = *(const bf16x8*)(&s_lds[(w * 16 + l15) * SW + kk * 32 + quad * 8]);
    __builtin_amdgcn_s_setprio(1);
#pragma unroll
    for (int j2 = 0; j2 < 4; ++j2)
      o[j2] = __builtin_amdgcn_mfma_f32_16x16x32_bf16(ap, vb0[j2], o[j2], 0, 0, 0);
    __builtin_amdgcn_s_setprio(0);
  };

#pragma unroll
  for (int jtp = 0; jtp < 6; ++jtp) {
    QK(2 * jtp);
    QK(2 * jtp + 1);
    PV(jtp);
    // prefetch V for kk=jtp+1 (kk<=6 always valid); WAR-safe: issued after PV MFMAs
#pragma unroll
    for (int j2 = 0; j2 < 4; ++j2)
      vb0[j2] = *(const bf16x8*)(vg + (j2 * 16 + l15) * VTP_ + (jtp + 1) * 32 + quad * 8);
  }
  QK(12);
  PV(6);   // cols 192..223: jt12's 192..207 + zeroed pads

  // row-sum reduce (within quad-groups) and normalize at store
#pragma unroll
  for (int r = 0; r < 4; ++r) {
    sum[r] += __shfl_xor(sum[r], 1);
    sum[r] += __shfl_xor(sum[r], 2);
    sum[r] += __shfl_xor(sum[r], 4);
    sum[r] += __shfl_xor(sum[r], 8);
  }
  float inv[4];
#pragma unroll
  for (int r = 0; r < 4; ++r) inv[r] = 1.0f / fmaxf(sum[r], 1e-20f);

#pragma unroll
  for (int j2 = 0; j2 < 4; ++j2) {
#pragma unroll
    for (int r = 0; r < 4; ++r) {
      int row = qt * 64 + w * 16 + quad * 4 + r;
      int hd = j2 * 16 + l15;
      if (row < N_)
        out[((size_t)b * N_ + row) * C_ + h * HD_ + hd] = (bf16)(o[j2][r] * inv[r]);
    }
  }
}

// ---------------- launch ----------------
extern "C" void kernel_launch(void* const* d_in, const int* in_sizes, int n_in,
                              void* d_out, int out_size, void* d_ws, size_t ws_size,
                              hipStream_t stream)
{
  const float* x      = (const float*)d_in[0];
  const float* qkv_w  = (const float*)d_in[1];
  const float* q_bias = (const float*)d_in[2];
  const float* v_bias = (const float*)d_in[3];
  const float* q_la   = (const float*)d_in[4];
  const float* q_lb   = (const float*)d_in[5];
  const float* k_la   = (const float*)d_in[6];
  const float* k_lb   = (const float*)d_in[7];
  const float* v_la   = (const float*)d_in[8];
  const float* v_lb   = (const float*)d_in[9];
  const float* rpt    = (const float*)d_in[10];
  const float* proj_w = (const float*)d_in[11];
  const float* proj_b = (const float*)d_in[12];
  const int*   rpi    = (const int*)d_in[13];
  float* out = (float*)d_out;

  char* ws = (char*)d_ws;
  // layout (16B-aligned); xbf dead after gemm<0>, reused as aout
  bf16*  xbf   = (bf16*)(ws);                         // 19,365,888 B
  bf16*  aout  = (bf16*)(ws);                         // alias
  bf16*  weff  = (bf16*)(ws + 19365888);              //  3,538,944 B
  float* biasf = (float*)(ws + 22904832);             //      9,216 B
  bf16*  pwbf  = (bf16*)(ws + 22914048);              //  1,179,648 B
  bf16*  qbuf  = (bf16*)(ws + 24093696);              // 19,365,888 B
  bf16*  kbuf  = (bf16*)(ws + 43459584);              // 19,365,888 B
  bf16*  vbufT = (bf16*)(ws + 62825472);              // 19,660,800 (+128 slack)
  bf16*  rpbT  = (bf16*)(ws + 82486400);              // 945,600
  // total ws use ≈ 83.4 MB

  prep_kernel<<<13748, 256, 0, stream>>>(
      x, proj_w, qkv_w, q_bias, v_bias, q_la, q_lb, k_la, k_lb, v_la, v_lb,
      rpt, rpi, xbf, pwbf, weff, biasf, rpbT);

  gemm_bt<0, 128><<<dim3(18, 99), 512, 0, stream>>>(
      xbf, weff, biasf, nullptr, M_, 3 * C_, C_, qbuf, kbuf, vbufT);

  // flat 3072-block grid; XCD-chunked swizzle inside the kernel
  attn_kernel<<<dim3(3072), 256, 0, stream>>>(qbuf, kbuf, vbufT, rpbT, aout);

  gemm_bt<1, 128><<<dim3(6, 99), 512, 0, stream>>>(
      aout, pwbf, proj_b, out, M_, C_, C_, nullptr, nullptr, nullptr);
}